// Round 1
// baseline (5893.601 us; speedup 1.0000x reference)
//
#include <hip/hip_runtime.h>
#include <math.h>

#define N_NODES 100000
#define N_EDGES 1600000
#define F 128

// ---------------------------------------------------------------- degrees
__global__ __launch_bounds__(256) void deg_kernel(const int* __restrict__ src,
                                                  const int* __restrict__ dst,
                                                  float* __restrict__ dout,
                                                  float* __restrict__ din, int E)
{
    int e = blockIdx.x * 256 + threadIdx.x;
    if (e < E) {
        atomicAdd(&dout[src[e]], 1.0f);
        atomicAdd(&din[dst[e]], 1.0f);
    }
}

__global__ __launch_bounds__(256) void rsqrt_kernel(float* __restrict__ dout,
                                                    float* __restrict__ din, int N)
{
    int i = blockIdx.x * 256 + threadIdx.x;
    if (i < N) {
        dout[i] = 1.0f / sqrtf(fmaxf(dout[i], 1.0f));
        din[i]  = 1.0f / sqrtf(fmaxf(din[i], 1.0f));
    }
}

// ---------------------------------------------------------------- GEMM
// Y[M,128] = diag(srow) * X[M,128] @ W[128,128]   (fp32, vector ALU)
// block = 256 threads, tile = 32 rows x 128 cols, per-thread 4x4 via float4
__global__ __launch_bounds__(256) void gemm128(const float* __restrict__ X,
                                               const float* __restrict__ srow,
                                               const float* __restrict__ W,
                                               float* __restrict__ Y)
{
    __shared__ float Ws[64 * 128];   // half of W (k-tiled) : 32 KB
    __shared__ float Xs[32 * 128];   // 32 scaled rows      : 16 KB
    const int tid = threadIdx.x;
    const int tx = tid & 31;   // col group: cols tx*4 .. tx*4+3
    const int ty = tid >> 5;   // row group: rows ty*4 .. ty*4+3
    const int row0 = blockIdx.x * 32;

    // stage X rows, scaled by srow
    for (int i = tid; i < 32 * 32; i += 256) {
        int r = i >> 5, c = i & 31;
        float4 v = reinterpret_cast<const float4*>(X)[(size_t)(row0 + r) * 32 + c];
        float s = srow[row0 + r];
        v.x *= s; v.y *= s; v.z *= s; v.w *= s;
        reinterpret_cast<float4*>(Xs)[r * 32 + c] = v;
    }

    float4 acc[4];
    acc[0] = acc[1] = acc[2] = acc[3] = make_float4(0.f, 0.f, 0.f, 0.f);

    for (int kt = 0; kt < 128; kt += 64) {
        __syncthreads();   // protect Ws (prev iter) and Xs (first iter)
        for (int i = tid; i < 64 * 32; i += 256)
            reinterpret_cast<float4*>(Ws)[i] =
                reinterpret_cast<const float4*>(W + kt * 128)[i];
        __syncthreads();

        for (int k = 0; k < 64; k += 4) {
            float4 wv[4], xv[4];
            #pragma unroll
            for (int kk = 0; kk < 4; kk++)
                wv[kk] = reinterpret_cast<float4*>(Ws)[(k + kk) * 32 + tx];
            #pragma unroll
            for (int rr = 0; rr < 4; rr++)
                xv[rr] = *reinterpret_cast<float4*>(&Xs[(ty * 4 + rr) * 128 + kt + k]);
            #pragma unroll
            for (int rr = 0; rr < 4; rr++) {
                acc[rr].x += xv[rr].x * wv[0].x + xv[rr].y * wv[1].x +
                             xv[rr].z * wv[2].x + xv[rr].w * wv[3].x;
                acc[rr].y += xv[rr].x * wv[0].y + xv[rr].y * wv[1].y +
                             xv[rr].z * wv[2].y + xv[rr].w * wv[3].y;
                acc[rr].z += xv[rr].x * wv[0].z + xv[rr].y * wv[1].z +
                             xv[rr].z * wv[2].z + xv[rr].w * wv[3].z;
                acc[rr].w += xv[rr].x * wv[0].w + xv[rr].y * wv[1].w +
                             xv[rr].z * wv[2].w + xv[rr].w * wv[3].w;
            }
        }
    }

    #pragma unroll
    for (int rr = 0; rr < 4; rr++) {
        int r = row0 + ty * 4 + rr;
        reinterpret_cast<float4*>(Y)[(size_t)r * 32 + tx] = acc[rr];
    }
}

// ---------------------------------------------------------------- scatter-add
// agg[dst[e]] += H[src[e]]  (per-edge 128 floats; 32 threads/edge, float4 lanes)
__global__ __launch_bounds__(256) void scatter(const float* __restrict__ H,
                                               const int* __restrict__ src,
                                               const int* __restrict__ dst,
                                               float* __restrict__ agg, int E)
{
    int t = blockIdx.x * 256 + threadIdx.x;
    int e = t >> 5;
    if (e >= E) return;
    int q = t & 31;
    int s = src[e], d = dst[e];
    float4 v = reinterpret_cast<const float4*>(H)[(size_t)s * 32 + q];
    float* ap = &agg[(size_t)d * 128 + q * 4];
    atomicAdd(ap + 0, v.x);
    atomicAdd(ap + 1, v.y);
    atomicAdd(ap + 2, v.z);
    atomicAdd(ap + 3, v.w);
}

// ---------------------------------------------------------------- post-agg
// Y = relu(agg * sin[row] + bias[col])
__global__ __launch_bounds__(256) void postagg(const float* __restrict__ agg,
                                               const float* __restrict__ sin_,
                                               const float* __restrict__ bias,
                                               float* __restrict__ Y, int N)
{
    int idx = blockIdx.x * 256 + threadIdx.x;   // float4 index
    if (idx < N * 32) {
        int r = idx >> 5, c = idx & 31;
        float s = sin_[r];
        float4 a = reinterpret_cast<const float4*>(agg)[idx];
        float4 b = reinterpret_cast<const float4*>(bias)[c];
        float4 o;
        o.x = fmaxf(a.x * s + b.x, 0.f);
        o.y = fmaxf(a.y * s + b.y, 0.f);
        o.z = fmaxf(a.z * s + b.z, 0.f);
        o.w = fmaxf(a.w * s + b.w, 0.f);
        reinterpret_cast<float4*>(Y)[idx] = o;
    }
}

// ---------------------------------------------------------------- classifier
// out[N,4] = H[N,128] @ Wc[128,4] + bc
__global__ __launch_bounds__(256) void classifier(const float* __restrict__ H,
                                                  const float* __restrict__ Wc,
                                                  const float* __restrict__ bc,
                                                  float* __restrict__ out, int N)
{
    __shared__ float4 Wcs[128];   // row k -> 4 cols
    for (int i = threadIdx.x; i < 128; i += 256)
        Wcs[i] = reinterpret_cast<const float4*>(Wc)[i];
    __syncthreads();
    int i = blockIdx.x * 256 + threadIdx.x;
    if (i < N) {
        float4 acc = reinterpret_cast<const float4*>(bc)[0];
        const float4* h4 = reinterpret_cast<const float4*>(H) + (size_t)i * 32;
        #pragma unroll
        for (int k4 = 0; k4 < 32; k4++) {
            float4 h = h4[k4];
            float4 w0 = Wcs[k4 * 4 + 0], w1 = Wcs[k4 * 4 + 1];
            float4 w2 = Wcs[k4 * 4 + 2], w3 = Wcs[k4 * 4 + 3];
            acc.x += h.x * w0.x + h.y * w1.x + h.z * w2.x + h.w * w3.x;
            acc.y += h.x * w0.y + h.y * w1.y + h.z * w2.y + h.w * w3.y;
            acc.z += h.x * w0.z + h.y * w1.z + h.z * w2.z + h.w * w3.z;
            acc.w += h.x * w0.w + h.y * w1.w + h.z * w2.w + h.w * w3.w;
        }
        reinterpret_cast<float4*>(out)[i] = acc;
    }
}

// ---------------------------------------------------------------- launch
extern "C" void kernel_launch(void* const* d_in, const int* in_sizes, int n_in,
                              void* d_out, int out_size, void* d_ws, size_t ws_size,
                              hipStream_t stream)
{
    const float* features = (const float*)d_in[0];
    const int*   src      = (const int*)d_in[1];
    const int*   dst      = (const int*)d_in[2];
    const float* W1       = (const float*)d_in[3];
    const float* b1       = (const float*)d_in[4];
    const float* W2       = (const float*)d_in[5];
    const float* b2       = (const float*)d_in[6];
    const float* Wc       = (const float*)d_in[7];
    const float* bc       = (const float*)d_in[8];
    float* out = (float*)d_out;

    char* ws = (char*)d_ws;
    float* sout = (float*)(ws);                 // [N] out-degree -> rsqrt scale
    float* sin_ = (float*)(ws + (1 << 19));     // [N] in-degree  -> rsqrt scale
    float* bufA = (float*)(ws + (1 << 20));                                // [N,128]
    float* bufB = (float*)(ws + (1 << 20) + (size_t)N_NODES * F * 4);      // [N,128]

    const int N = N_NODES, E = N_EDGES;

    // degrees
    hipMemsetAsync(sout, 0, N * sizeof(float), stream);
    hipMemsetAsync(sin_, 0, N * sizeof(float), stream);
    deg_kernel<<<(E + 255) / 256, 256, 0, stream>>>(src, dst, sout, sin_, E);
    rsqrt_kernel<<<(N + 255) / 256, 256, 0, stream>>>(sout, sin_, N);

    // layer 1: proj -> aggregate -> norm+bias+relu
    gemm128<<<N / 32, 256, 0, stream>>>(features, sout, W1, bufA);
    hipMemsetAsync(bufB, 0, (size_t)N * F * 4, stream);
    scatter<<<(E * 32) / 256, 256, 0, stream>>>(bufA, src, dst, bufB, E);
    postagg<<<(N * 32 + 255) / 256, 256, 0, stream>>>(bufB, sin_, b1, bufA, N);

    // layer 2
    gemm128<<<N / 32, 256, 0, stream>>>(bufA, sout, W2, bufB);
    hipMemsetAsync(bufA, 0, (size_t)N * F * 4, stream);
    scatter<<<(E * 32) / 256, 256, 0, stream>>>(bufB, src, dst, bufA, E);
    postagg<<<(N * 32 + 255) / 256, 256, 0, stream>>>(bufA, sin_, b2, bufB, N);

    // classifier
    classifier<<<(N + 255) / 256, 256, 0, stream>>>(bufB, Wc, bc, out, N);
}

// Round 2
// 1035.280 us; speedup vs baseline: 5.6928x; 5.6928x over previous
//
#include <hip/hip_runtime.h>
#include <math.h>

#define N_NODES 100000
#define N_EDGES 1600000
#define F 128

// ---------------------------------------------------------------- degrees (int)
__global__ __launch_bounds__(256) void deg_kernel(const int* __restrict__ src,
                                                  const int* __restrict__ dst,
                                                  int* __restrict__ cout_,
                                                  int* __restrict__ cin_, int E)
{
    int e = blockIdx.x * 256 + threadIdx.x;
    if (e < E) {
        atomicAdd(&cout_[src[e]], 1);
        atomicAdd(&cin_[dst[e]], 1);
    }
}

__global__ __launch_bounds__(256) void rsqrt_kernel(const int* __restrict__ cout_,
                                                    const int* __restrict__ cin_,
                                                    float* __restrict__ sout,
                                                    float* __restrict__ sin_, int N)
{
    int i = blockIdx.x * 256 + threadIdx.x;
    if (i < N) {
        sout[i] = 1.0f / sqrtf((float)max(cout_[i], 1));
        sin_[i] = 1.0f / sqrtf((float)max(cin_[i], 1));
    }
}

// ---------------------------------------------------------------- prefix scan
// single block, 1024 threads: exclusive scan of cnt[N] -> row_ptr[N+1], cursor[N]
__global__ __launch_bounds__(1024) void scan_kernel(const int* __restrict__ cnt,
                                                    int* __restrict__ row_ptr,
                                                    int* __restrict__ cursor, int N)
{
    __shared__ int sums[1024];
    const int tid = threadIdx.x;
    const int chunk = (N + 1023) / 1024;
    int beg = tid * chunk;
    int end = min(beg + chunk, N);
    int s = 0;
    for (int i = beg; i < end; i++) s += cnt[i];
    sums[tid] = s;
    __syncthreads();
    for (int off = 1; off < 1024; off <<= 1) {
        int t = (tid >= off) ? sums[tid - off] : 0;
        __syncthreads();
        sums[tid] += t;
        __syncthreads();
    }
    int running = sums[tid] - s;   // exclusive prefix of this thread's chunk
    for (int i = beg; i < end; i++) {
        row_ptr[i] = running;
        cursor[i] = running;
        running += cnt[i];
    }
    if (tid == 1023) row_ptr[N] = sums[1023];
}

// ---------------------------------------------------------------- CSR fill
__global__ __launch_bounds__(256) void fill_kernel(const int* __restrict__ src,
                                                   const int* __restrict__ dst,
                                                   int* __restrict__ cursor,
                                                   int* __restrict__ col, int E)
{
    int e = blockIdx.x * 256 + threadIdx.x;
    if (e < E) {
        int pos = atomicAdd(&cursor[dst[e]], 1);
        col[pos] = src[e];
    }
}

// ---------------------------------------------------------------- GEMM
// Y[M,128] = diag(srow) * X[M,128] @ W[128,128]   (fp32, vector ALU)
__global__ __launch_bounds__(256) void gemm128(const float* __restrict__ X,
                                               const float* __restrict__ srow,
                                               const float* __restrict__ W,
                                               float* __restrict__ Y)
{
    __shared__ float Ws[64 * 128];
    __shared__ float Xs[32 * 128];
    const int tid = threadIdx.x;
    const int tx = tid & 31;
    const int ty = tid >> 5;
    const int row0 = blockIdx.x * 32;

    for (int i = tid; i < 32 * 32; i += 256) {
        int r = i >> 5, c = i & 31;
        float4 v = reinterpret_cast<const float4*>(X)[(size_t)(row0 + r) * 32 + c];
        float s = srow[row0 + r];
        v.x *= s; v.y *= s; v.z *= s; v.w *= s;
        reinterpret_cast<float4*>(Xs)[r * 32 + c] = v;
    }

    float4 acc[4];
    acc[0] = acc[1] = acc[2] = acc[3] = make_float4(0.f, 0.f, 0.f, 0.f);

    for (int kt = 0; kt < 128; kt += 64) {
        __syncthreads();
        for (int i = tid; i < 64 * 32; i += 256)
            reinterpret_cast<float4*>(Ws)[i] =
                reinterpret_cast<const float4*>(W + kt * 128)[i];
        __syncthreads();

        for (int k = 0; k < 64; k += 4) {
            float4 wv[4], xv[4];
            #pragma unroll
            for (int kk = 0; kk < 4; kk++)
                wv[kk] = reinterpret_cast<float4*>(Ws)[(k + kk) * 32 + tx];
            #pragma unroll
            for (int rr = 0; rr < 4; rr++)
                xv[rr] = *reinterpret_cast<float4*>(&Xs[(ty * 4 + rr) * 128 + kt + k]);
            #pragma unroll
            for (int rr = 0; rr < 4; rr++) {
                acc[rr].x += xv[rr].x * wv[0].x + xv[rr].y * wv[1].x +
                             xv[rr].z * wv[2].x + xv[rr].w * wv[3].x;
                acc[rr].y += xv[rr].x * wv[0].y + xv[rr].y * wv[1].y +
                             xv[rr].z * wv[2].y + xv[rr].w * wv[3].y;
                acc[rr].z += xv[rr].x * wv[0].z + xv[rr].y * wv[1].z +
                             xv[rr].z * wv[2].z + xv[rr].w * wv[3].z;
                acc[rr].w += xv[rr].x * wv[0].w + xv[rr].y * wv[1].w +
                             xv[rr].z * wv[2].w + xv[rr].w * wv[3].w;
            }
        }
    }

    #pragma unroll
    for (int rr = 0; rr < 4; rr++) {
        int r = row0 + ty * 4 + rr;
        reinterpret_cast<float4*>(Y)[(size_t)r * 32 + tx] = acc[rr];
    }
}

// ---------------------------------------------------------------- gather-aggregate
// one wave per node: Y[n] = relu( (sum_{e in CSR[n]} H[col[e]]) * sin_[n] + bias )
__global__ __launch_bounds__(256) void gather_agg(const float* __restrict__ H,
                                                  const int* __restrict__ row_ptr,
                                                  const int* __restrict__ col,
                                                  const float* __restrict__ sin_,
                                                  const float* __restrict__ bias,
                                                  float* __restrict__ Y, int N)
{
    int node = blockIdx.x * 4 + (threadIdx.x >> 6);
    if (node >= N) return;
    int lane = threadIdx.x & 63;
    int beg = row_ptr[node], end = row_ptr[node + 1];
    const float2* H2 = reinterpret_cast<const float2*>(H);
    float2 acc = make_float2(0.f, 0.f);
    int i = beg;
    for (; i + 3 < end; i += 4) {   // unroll 4: expose 4 independent loads
        int s0 = col[i], s1 = col[i + 1], s2 = col[i + 2], s3 = col[i + 3];
        float2 v0 = H2[(size_t)s0 * 64 + lane];
        float2 v1 = H2[(size_t)s1 * 64 + lane];
        float2 v2 = H2[(size_t)s2 * 64 + lane];
        float2 v3 = H2[(size_t)s3 * 64 + lane];
        acc.x += v0.x + v1.x + v2.x + v3.x;
        acc.y += v0.y + v1.y + v2.y + v3.y;
    }
    for (; i < end; i++) {
        int s = col[i];
        float2 v = H2[(size_t)s * 64 + lane];
        acc.x += v.x; acc.y += v.y;
    }
    float sc = sin_[node];
    float2 b = reinterpret_cast<const float2*>(bias)[lane];
    float2 o;
    o.x = fmaxf(acc.x * sc + b.x, 0.f);
    o.y = fmaxf(acc.y * sc + b.y, 0.f);
    reinterpret_cast<float2*>(Y)[(size_t)node * 64 + lane] = o;
}

// ---------------------------------------------------------------- classifier
__global__ __launch_bounds__(256) void classifier(const float* __restrict__ H,
                                                  const float* __restrict__ Wc,
                                                  const float* __restrict__ bc,
                                                  float* __restrict__ out, int N)
{
    __shared__ float4 Wcs[128];
    for (int i = threadIdx.x; i < 128; i += 256)
        Wcs[i] = reinterpret_cast<const float4*>(Wc)[i];
    __syncthreads();
    int i = blockIdx.x * 256 + threadIdx.x;
    if (i < N) {
        float4 acc = reinterpret_cast<const float4*>(bc)[0];
        const float4* h4 = reinterpret_cast<const float4*>(H) + (size_t)i * 32;
        #pragma unroll
        for (int k4 = 0; k4 < 32; k4++) {
            float4 h = h4[k4];
            float4 w0 = Wcs[k4 * 4 + 0], w1 = Wcs[k4 * 4 + 1];
            float4 w2 = Wcs[k4 * 4 + 2], w3 = Wcs[k4 * 4 + 3];
            acc.x += h.x * w0.x + h.y * w1.x + h.z * w2.x + h.w * w3.x;
            acc.y += h.x * w0.y + h.y * w1.y + h.z * w2.y + h.w * w3.y;
            acc.z += h.x * w0.z + h.y * w1.z + h.z * w2.z + h.w * w3.z;
            acc.w += h.x * w0.w + h.y * w1.w + h.z * w2.w + h.w * w3.w;
        }
        reinterpret_cast<float4*>(out)[i] = acc;
    }
}

// ---------------------------------------------------------------- launch
extern "C" void kernel_launch(void* const* d_in, const int* in_sizes, int n_in,
                              void* d_out, int out_size, void* d_ws, size_t ws_size,
                              hipStream_t stream)
{
    const float* features = (const float*)d_in[0];
    const int*   src      = (const int*)d_in[1];
    const int*   dst      = (const int*)d_in[2];
    const float* W1       = (const float*)d_in[3];
    const float* b1       = (const float*)d_in[4];
    const float* W2       = (const float*)d_in[5];
    const float* b2       = (const float*)d_in[6];
    const float* Wc       = (const float*)d_in[7];
    const float* bc       = (const float*)d_in[8];
    float* out = (float*)d_out;

    char* ws = (char*)d_ws;
    const size_t MB = 1 << 20;
    int*   cnt_out = (int*)(ws + 0 * MB);            // N ints
    int*   cnt_in  = (int*)(ws + 1 * MB);            // N ints
    float* sout    = (float*)(ws + 2 * MB);          // N floats
    float* sin_    = (float*)(ws + 3 * MB);          // N floats
    int*   row_ptr = (int*)(ws + 4 * MB);            // N+1 ints
    int*   cursor  = (int*)(ws + 5 * MB);            // N ints
    int*   col     = (int*)(ws + 6 * MB);            // E ints (6.4 MB)
    float* bufA    = (float*)(ws + 13 * MB);                                 // [N,128]
    float* bufB    = (float*)(ws + 13 * MB + (size_t)N_NODES * F * 4);       // [N,128]

    const int N = N_NODES, E = N_EDGES;

    // ---- CSR build + degree norms
    hipMemsetAsync(cnt_out, 0, N * sizeof(int), stream);
    hipMemsetAsync(cnt_in, 0, N * sizeof(int), stream);
    deg_kernel<<<(E + 255) / 256, 256, 0, stream>>>(src, dst, cnt_out, cnt_in, E);
    rsqrt_kernel<<<(N + 255) / 256, 256, 0, stream>>>(cnt_out, cnt_in, sout, sin_, N);
    scan_kernel<<<1, 1024, 0, stream>>>(cnt_in, row_ptr, cursor, N);
    fill_kernel<<<(E + 255) / 256, 256, 0, stream>>>(src, dst, cursor, col, E);

    // ---- layer 1
    gemm128<<<N / 32, 256, 0, stream>>>(features, sout, W1, bufA);
    gather_agg<<<(N + 3) / 4, 256, 0, stream>>>(bufA, row_ptr, col, sin_, b1, bufB, N);

    // ---- layer 2
    gemm128<<<N / 32, 256, 0, stream>>>(bufB, sout, W2, bufA);
    gather_agg<<<(N + 3) / 4, 256, 0, stream>>>(bufA, row_ptr, col, sin_, b2, bufB, N);

    // ---- classifier
    classifier<<<(N + 255) / 256, 256, 0, stream>>>(bufB, Wc, bc, out, N);
}

// Round 3
// 815.617 us; speedup vs baseline: 7.2259x; 1.2693x over previous
//
#include <hip/hip_runtime.h>
#include <math.h>

#define N_NODES 100000
#define N_EDGES 1600000
#define F 128
#define SCAN_B 256

// ---------------------------------------------------------------- degrees (int)
__global__ __launch_bounds__(256) void deg_kernel(const int* __restrict__ src,
                                                  const int* __restrict__ dst,
                                                  int* __restrict__ cout_,
                                                  int* __restrict__ cin_, int E)
{
    int e = blockIdx.x * 256 + threadIdx.x;
    if (e < E) {
        atomicAdd(&cout_[src[e]], 1);
        atomicAdd(&cin_[dst[e]], 1);
    }
}

__global__ __launch_bounds__(256) void rsqrt_kernel(const int* __restrict__ cout_,
                                                    const int* __restrict__ cin_,
                                                    float* __restrict__ sout,
                                                    float* __restrict__ sin_, int N)
{
    int i = blockIdx.x * 256 + threadIdx.x;
    if (i < N) {
        sout[i] = 1.0f / sqrtf((float)max(cout_[i], 1));
        sin_[i] = 1.0f / sqrtf((float)max(cin_[i], 1));
    }
}

// ---------------------------------------------------------------- two-level scan
__global__ __launch_bounds__(SCAN_B) void scan_partial(const int* __restrict__ cnt,
                                                       int* __restrict__ bsum, int N)
{
    __shared__ int s[SCAN_B];
    int i = blockIdx.x * SCAN_B + threadIdx.x;
    s[threadIdx.x] = (i < N) ? cnt[i] : 0;
    __syncthreads();
    for (int off = SCAN_B / 2; off > 0; off >>= 1) {
        if (threadIdx.x < off) s[threadIdx.x] += s[threadIdx.x + off];
        __syncthreads();
    }
    if (threadIdx.x == 0) bsum[blockIdx.x] = s[0];
}

// single small block: exclusive offsets of the block sums (nb <= 512)
__global__ __launch_bounds__(512) void scan_bsums(const int* __restrict__ bsum,
                                                  int* __restrict__ bofs, int nb)
{
    __shared__ int s[512];
    int t = threadIdx.x;
    int v = (t < nb) ? bsum[t] : 0;
    s[t] = v;
    __syncthreads();
    for (int off = 1; off < 512; off <<= 1) {
        int u = (t >= off) ? s[t - off] : 0;
        __syncthreads();
        s[t] += u;
        __syncthreads();
    }
    if (t < nb) bofs[t] = s[t] - v;   // exclusive
}

__global__ __launch_bounds__(SCAN_B) void scan_final(const int* __restrict__ cnt,
                                                     const int* __restrict__ bofs,
                                                     int* __restrict__ row_ptr,
                                                     int* __restrict__ cursor,
                                                     int N, int E)
{
    __shared__ int s[SCAN_B];
    int i = blockIdx.x * SCAN_B + threadIdx.x;
    int v = (i < N) ? cnt[i] : 0;
    s[threadIdx.x] = v;
    __syncthreads();
    for (int off = 1; off < SCAN_B; off <<= 1) {
        int u = (threadIdx.x >= off) ? s[threadIdx.x - off] : 0;
        __syncthreads();
        s[threadIdx.x] += u;
        __syncthreads();
    }
    if (i < N) {
        int ex = bofs[blockIdx.x] + s[threadIdx.x] - v;   // exclusive prefix
        row_ptr[i] = ex;
        cursor[i] = ex;
    }
    if (i == 0) row_ptr[N] = E;
}

// ---------------------------------------------------------------- CSR fill
__global__ __launch_bounds__(256) void fill_kernel(const int* __restrict__ src,
                                                   const int* __restrict__ dst,
                                                   int* __restrict__ cursor,
                                                   int* __restrict__ col, int E)
{
    int e = blockIdx.x * 256 + threadIdx.x;
    if (e < E) {
        int pos = atomicAdd(&cursor[dst[e]], 1);
        col[pos] = src[e];
    }
}

// ---------------------------------------------------------------- GEMM
// Y[M,128] = diag(srow) * X[M,128] @ W[128,128]   (fp32, vector ALU)
__global__ __launch_bounds__(256) void gemm128(const float* __restrict__ X,
                                               const float* __restrict__ srow,
                                               const float* __restrict__ W,
                                               float* __restrict__ Y)
{
    __shared__ float Ws[64 * 128];
    __shared__ float Xs[32 * 128];
    const int tid = threadIdx.x;
    const int tx = tid & 31;
    const int ty = tid >> 5;
    const int row0 = blockIdx.x * 32;

    for (int i = tid; i < 32 * 32; i += 256) {
        int r = i >> 5, c = i & 31;
        float4 v = reinterpret_cast<const float4*>(X)[(size_t)(row0 + r) * 32 + c];
        float s = srow[row0 + r];
        v.x *= s; v.y *= s; v.z *= s; v.w *= s;
        reinterpret_cast<float4*>(Xs)[r * 32 + c] = v;
    }

    float4 acc[4];
    acc[0] = acc[1] = acc[2] = acc[3] = make_float4(0.f, 0.f, 0.f, 0.f);

    for (int kt = 0; kt < 128; kt += 64) {
        __syncthreads();
        for (int i = tid; i < 64 * 32; i += 256)
            reinterpret_cast<float4*>(Ws)[i] =
                reinterpret_cast<const float4*>(W + kt * 128)[i];
        __syncthreads();

        for (int k = 0; k < 64; k += 4) {
            float4 wv[4], xv[4];
            #pragma unroll
            for (int kk = 0; kk < 4; kk++)
                wv[kk] = reinterpret_cast<float4*>(Ws)[(k + kk) * 32 + tx];
            #pragma unroll
            for (int rr = 0; rr < 4; rr++)
                xv[rr] = *reinterpret_cast<float4*>(&Xs[(ty * 4 + rr) * 128 + kt + k]);
            #pragma unroll
            for (int rr = 0; rr < 4; rr++) {
                acc[rr].x += xv[rr].x * wv[0].x + xv[rr].y * wv[1].x +
                             xv[rr].z * wv[2].x + xv[rr].w * wv[3].x;
                acc[rr].y += xv[rr].x * wv[0].y + xv[rr].y * wv[1].y +
                             xv[rr].z * wv[2].y + xv[rr].w * wv[3].y;
                acc[rr].z += xv[rr].x * wv[0].z + xv[rr].y * wv[1].z +
                             xv[rr].z * wv[2].z + xv[rr].w * wv[3].z;
                acc[rr].w += xv[rr].x * wv[0].w + xv[rr].y * wv[1].w +
                             xv[rr].z * wv[2].w + xv[rr].w * wv[3].w;
            }
        }
    }

    #pragma unroll
    for (int rr = 0; rr < 4; rr++) {
        int r = row0 + ty * 4 + rr;
        reinterpret_cast<float4*>(Y)[(size_t)r * 32 + tx] = acc[rr];
    }
}

// ---------------------------------------------------------------- gather-aggregate
// one wave per node: Y[n] = relu( (sum_{e in CSR[n]} H[col[e]]) * sin_[n] + bias )
__global__ __launch_bounds__(256) void gather_agg(const float* __restrict__ H,
                                                  const int* __restrict__ row_ptr,
                                                  const int* __restrict__ col,
                                                  const float* __restrict__ sin_,
                                                  const float* __restrict__ bias,
                                                  float* __restrict__ Y, int N)
{
    int node = blockIdx.x * 4 + (threadIdx.x >> 6);
    if (node >= N) return;
    int lane = threadIdx.x & 63;
    int beg = row_ptr[node], end = row_ptr[node + 1];
    const float2* H2 = reinterpret_cast<const float2*>(H);
    float2 acc = make_float2(0.f, 0.f);
    int i = beg;
    for (; i + 3 < end; i += 4) {
        int s0 = col[i], s1 = col[i + 1], s2 = col[i + 2], s3 = col[i + 3];
        float2 v0 = H2[(size_t)s0 * 64 + lane];
        float2 v1 = H2[(size_t)s1 * 64 + lane];
        float2 v2 = H2[(size_t)s2 * 64 + lane];
        float2 v3 = H2[(size_t)s3 * 64 + lane];
        acc.x += v0.x + v1.x + v2.x + v3.x;
        acc.y += v0.y + v1.y + v2.y + v3.y;
    }
    for (; i < end; i++) {
        int s = col[i];
        float2 v = H2[(size_t)s * 64 + lane];
        acc.x += v.x; acc.y += v.y;
    }
    float sc = sin_[node];
    float2 b = reinterpret_cast<const float2*>(bias)[lane];
    float2 o;
    o.x = fmaxf(acc.x * sc + b.x, 0.f);
    o.y = fmaxf(acc.y * sc + b.y, 0.f);
    reinterpret_cast<float2*>(Y)[(size_t)node * 64 + lane] = o;
}

// ---------------------------------------------------------------- classifier
__global__ __launch_bounds__(256) void classifier(const float* __restrict__ H,
                                                  const float* __restrict__ Wc,
                                                  const float* __restrict__ bc,
                                                  float* __restrict__ out, int N)
{
    __shared__ float4 Wcs[128];
    for (int i = threadIdx.x; i < 128; i += 256)
        Wcs[i] = reinterpret_cast<const float4*>(Wc)[i];
    __syncthreads();
    int i = blockIdx.x * 256 + threadIdx.x;
    if (i < N) {
        float4 acc = reinterpret_cast<const float4*>(bc)[0];
        const float4* h4 = reinterpret_cast<const float4*>(H) + (size_t)i * 32;
        #pragma unroll
        for (int k4 = 0; k4 < 32; k4++) {
            float4 h = h4[k4];
            float4 w0 = Wcs[k4 * 4 + 0], w1 = Wcs[k4 * 4 + 1];
            float4 w2 = Wcs[k4 * 4 + 2], w3 = Wcs[k4 * 4 + 3];
            acc.x += h.x * w0.x + h.y * w1.x + h.z * w2.x + h.w * w3.x;
            acc.y += h.x * w0.y + h.y * w1.y + h.z * w2.y + h.w * w3.y;
            acc.z += h.x * w0.z + h.y * w1.z + h.z * w2.z + h.w * w3.z;
            acc.w += h.x * w0.w + h.y * w1.w + h.z * w2.w + h.w * w3.w;
        }
        reinterpret_cast<float4*>(out)[i] = acc;
    }
}

// ---------------------------------------------------------------- launch
extern "C" void kernel_launch(void* const* d_in, const int* in_sizes, int n_in,
                              void* d_out, int out_size, void* d_ws, size_t ws_size,
                              hipStream_t stream)
{
    const float* features = (const float*)d_in[0];
    const int*   src      = (const int*)d_in[1];
    const int*   dst      = (const int*)d_in[2];
    const float* W1       = (const float*)d_in[3];
    const float* b1       = (const float*)d_in[4];
    const float* W2       = (const float*)d_in[5];
    const float* b2       = (const float*)d_in[6];
    const float* Wc       = (const float*)d_in[7];
    const float* bc       = (const float*)d_in[8];
    float* out = (float*)d_out;

    char* ws = (char*)d_ws;
    const size_t MB = 1 << 20;
    int*   cnt_out = (int*)(ws + 0 * MB);            // N ints
    int*   cnt_in  = (int*)(ws + 1 * MB);            // N ints
    float* sout    = (float*)(ws + 2 * MB);          // N floats
    float* sin_    = (float*)(ws + 3 * MB);          // N floats
    int*   row_ptr = (int*)(ws + 4 * MB);            // N+1 ints
    int*   cursor  = (int*)(ws + 5 * MB);            // N ints
    int*   bsum    = (int*)(ws + 5 * MB + 512 * 1024);        // NBLK ints
    int*   bofs    = (int*)(ws + 5 * MB + 768 * 1024);        // NBLK ints
    int*   col     = (int*)(ws + 6 * MB);            // E ints (6.4 MB)
    float* bufA    = (float*)(ws + 13 * MB);                                 // [N,128]
    float* bufB    = (float*)(ws + 13 * MB + (size_t)N_NODES * F * 4);       // [N,128]

    const int N = N_NODES, E = N_EDGES;
    const int NBLK = (N + SCAN_B - 1) / SCAN_B;      // 391

    // ---- CSR build + degree norms
    hipMemsetAsync(cnt_out, 0, N * sizeof(int), stream);
    hipMemsetAsync(cnt_in, 0, N * sizeof(int), stream);
    deg_kernel<<<(E + 255) / 256, 256, 0, stream>>>(src, dst, cnt_out, cnt_in, E);
    rsqrt_kernel<<<(N + 255) / 256, 256, 0, stream>>>(cnt_out, cnt_in, sout, sin_, N);
    scan_partial<<<NBLK, SCAN_B, 0, stream>>>(cnt_in, bsum, N);
    scan_bsums<<<1, 512, 0, stream>>>(bsum, bofs, NBLK);
    scan_final<<<NBLK, SCAN_B, 0, stream>>>(cnt_in, bofs, row_ptr, cursor, N, E);
    fill_kernel<<<(E + 255) / 256, 256, 0, stream>>>(src, dst, cursor, col, E);

    // ---- layer 1
    gemm128<<<N / 32, 256, 0, stream>>>(features, sout, W1, bufA);
    gather_agg<<<(N + 3) / 4, 256, 0, stream>>>(bufA, row_ptr, col, sin_, b1, bufB, N);

    // ---- layer 2
    gemm128<<<N / 32, 256, 0, stream>>>(bufB, sout, W2, bufA);
    gather_agg<<<(N + 3) / 4, 256, 0, stream>>>(bufA, row_ptr, col, sin_, b2, bufB, N);

    // ---- classifier
    classifier<<<(N + 255) / 256, 256, 0, stream>>>(bufB, Wc, bc, out, N);
}

// Round 4
// 777.466 us; speedup vs baseline: 7.5805x; 1.0491x over previous
//
#include <hip/hip_runtime.h>
#include <math.h>

#define N_NODES 100000
#define N_EDGES 1600000
#define F 128
#define SCAN_B 256
#define EPT 8          // edges per thread in deg/fill

// ---------------------------------------------------------------- degrees (int)
// 8 edges/thread: 16 independent atomics in flight per thread (latency hiding)
__global__ __launch_bounds__(256) void deg_kernel(const int* __restrict__ src,
                                                  const int* __restrict__ dst,
                                                  int* __restrict__ cout_,
                                                  int* __restrict__ cin_, int E)
{
    int base = (blockIdx.x * 256 + threadIdx.x) * EPT;
    if (base + EPT <= E) {
        int4 s0 = *reinterpret_cast<const int4*>(src + base);
        int4 s1 = *reinterpret_cast<const int4*>(src + base + 4);
        int4 d0 = *reinterpret_cast<const int4*>(dst + base);
        int4 d1 = *reinterpret_cast<const int4*>(dst + base + 4);
        atomicAdd(&cout_[s0.x], 1); atomicAdd(&cin_[d0.x], 1);
        atomicAdd(&cout_[s0.y], 1); atomicAdd(&cin_[d0.y], 1);
        atomicAdd(&cout_[s0.z], 1); atomicAdd(&cin_[d0.z], 1);
        atomicAdd(&cout_[s0.w], 1); atomicAdd(&cin_[d0.w], 1);
        atomicAdd(&cout_[s1.x], 1); atomicAdd(&cin_[d1.x], 1);
        atomicAdd(&cout_[s1.y], 1); atomicAdd(&cin_[d1.y], 1);
        atomicAdd(&cout_[s1.z], 1); atomicAdd(&cin_[d1.z], 1);
        atomicAdd(&cout_[s1.w], 1); atomicAdd(&cin_[d1.w], 1);
    } else {
        for (int e = base; e < E; e++) {
            atomicAdd(&cout_[src[e]], 1);
            atomicAdd(&cin_[dst[e]], 1);
        }
    }
}

__global__ __launch_bounds__(256) void rsqrt_kernel(const int* __restrict__ cout_,
                                                    const int* __restrict__ cin_,
                                                    float* __restrict__ sout,
                                                    float* __restrict__ sin_, int N)
{
    int i = blockIdx.x * 256 + threadIdx.x;
    if (i < N) {
        sout[i] = 1.0f / sqrtf((float)max(cout_[i], 1));
        sin_[i] = 1.0f / sqrtf((float)max(cin_[i], 1));
    }
}

// ---------------------------------------------------------------- two-level scan
__global__ __launch_bounds__(SCAN_B) void scan_partial(const int* __restrict__ cnt,
                                                       int* __restrict__ bsum, int N)
{
    __shared__ int s[SCAN_B];
    int i = blockIdx.x * SCAN_B + threadIdx.x;
    s[threadIdx.x] = (i < N) ? cnt[i] : 0;
    __syncthreads();
    for (int off = SCAN_B / 2; off > 0; off >>= 1) {
        if (threadIdx.x < off) s[threadIdx.x] += s[threadIdx.x + off];
        __syncthreads();
    }
    if (threadIdx.x == 0) bsum[blockIdx.x] = s[0];
}

__global__ __launch_bounds__(512) void scan_bsums(const int* __restrict__ bsum,
                                                  int* __restrict__ bofs, int nb)
{
    __shared__ int s[512];
    int t = threadIdx.x;
    int v = (t < nb) ? bsum[t] : 0;
    s[t] = v;
    __syncthreads();
    for (int off = 1; off < 512; off <<= 1) {
        int u = (t >= off) ? s[t - off] : 0;
        __syncthreads();
        s[t] += u;
        __syncthreads();
    }
    if (t < nb) bofs[t] = s[t] - v;   // exclusive
}

__global__ __launch_bounds__(SCAN_B) void scan_final(const int* __restrict__ cnt,
                                                     const int* __restrict__ bofs,
                                                     int* __restrict__ row_ptr,
                                                     int* __restrict__ cursor,
                                                     int N, int E)
{
    __shared__ int s[SCAN_B];
    int i = blockIdx.x * SCAN_B + threadIdx.x;
    int v = (i < N) ? cnt[i] : 0;
    s[threadIdx.x] = v;
    __syncthreads();
    for (int off = 1; off < SCAN_B; off <<= 1) {
        int u = (threadIdx.x >= off) ? s[threadIdx.x - off] : 0;
        __syncthreads();
        s[threadIdx.x] += u;
        __syncthreads();
    }
    if (i < N) {
        int ex = bofs[blockIdx.x] + s[threadIdx.x] - v;
        row_ptr[i] = ex;
        cursor[i] = ex;
    }
    if (i == 0) row_ptr[N] = E;
}

// ---------------------------------------------------------------- CSR fill
// 8 edges/thread: 8 independent atomic->store chains in flight
__global__ __launch_bounds__(256) void fill_kernel(const int* __restrict__ src,
                                                   const int* __restrict__ dst,
                                                   int* __restrict__ cursor,
                                                   int* __restrict__ col, int E)
{
    int base = (blockIdx.x * 256 + threadIdx.x) * EPT;
    if (base + EPT <= E) {
        int4 s0 = *reinterpret_cast<const int4*>(src + base);
        int4 s1 = *reinterpret_cast<const int4*>(src + base + 4);
        int4 d0 = *reinterpret_cast<const int4*>(dst + base);
        int4 d1 = *reinterpret_cast<const int4*>(dst + base + 4);
        int p0 = atomicAdd(&cursor[d0.x], 1);
        int p1 = atomicAdd(&cursor[d0.y], 1);
        int p2 = atomicAdd(&cursor[d0.z], 1);
        int p3 = atomicAdd(&cursor[d0.w], 1);
        int p4 = atomicAdd(&cursor[d1.x], 1);
        int p5 = atomicAdd(&cursor[d1.y], 1);
        int p6 = atomicAdd(&cursor[d1.z], 1);
        int p7 = atomicAdd(&cursor[d1.w], 1);
        col[p0] = s0.x; col[p1] = s0.y; col[p2] = s0.z; col[p3] = s0.w;
        col[p4] = s1.x; col[p5] = s1.y; col[p6] = s1.z; col[p7] = s1.w;
    } else {
        for (int e = base; e < E; e++) {
            int pos = atomicAdd(&cursor[dst[e]], 1);
            col[pos] = src[e];
        }
    }
}

// ---------------------------------------------------------------- GEMM
// Y[N,128] = diag(srow) * X[N,128] @ W[128,128]   (fp32, vector ALU)
// block: 256 thr, tile 128x128, 8x8 micro-tile. W fully LDS-resident (64 KB);
// X staged transposed (Xs[k][m]) in 32-k chunks so x-frag reads broadcast.
// Thread (tx,ty): rows ty*8..+7, cols {tx*4..+3, 64+tx*4..+3} (coalesced stores).
__global__ __launch_bounds__(256) void gemm128(const float* __restrict__ X,
                                               const float* __restrict__ srow,
                                               const float* __restrict__ W,
                                               float* __restrict__ Y, int N)
{
    __shared__ float Ws[128 * 128];   // [k][n], 64 KB
    __shared__ float Xs[32 * 128];    // [k][m], 16 KB
    const int tid = threadIdx.x;
    const int tx = tid & 15;
    const int ty = tid >> 4;
    const int row0 = blockIdx.x * 128;

    for (int i = tid; i < 4096; i += 256)
        reinterpret_cast<float4*>(Ws)[i] = reinterpret_cast<const float4*>(W)[i];

    float acc[8][8];
    #pragma unroll
    for (int r = 0; r < 8; r++)
        #pragma unroll
        for (int c = 0; c < 8; c++) acc[r][c] = 0.f;

    const int m = tid & 127;          // staging row within tile
    const int half = tid >> 7;        // 0/1
    const int grow_s = row0 + m;
    const bool ok = grow_s < N;
    float s = ok ? srow[grow_s] : 0.f;

    for (int kc = 0; kc < 128; kc += 32) {
        __syncthreads();
        #pragma unroll
        for (int j = 0; j < 4; j++) {
            int k4 = half * 4 + j;    // float4 index within chunk (0..7)
            float4 v = ok ? reinterpret_cast<const float4*>(X)[(size_t)grow_s * 32 + (kc >> 2) + k4]
                          : make_float4(0.f, 0.f, 0.f, 0.f);
            int kb = k4 * 4;
            Xs[(kb + 0) * 128 + m] = v.x * s;
            Xs[(kb + 1) * 128 + m] = v.y * s;
            Xs[(kb + 2) * 128 + m] = v.z * s;
            Xs[(kb + 3) * 128 + m] = v.w * s;
        }
        __syncthreads();

        #pragma unroll
        for (int k = 0; k < 32; k++) {
            float4 xa = *reinterpret_cast<float4*>(&Xs[k * 128 + ty * 8]);
            float4 xb = *reinterpret_cast<float4*>(&Xs[k * 128 + ty * 8 + 4]);
            float4 wa = *reinterpret_cast<float4*>(&Ws[(kc + k) * 128 + tx * 4]);
            float4 wb = *reinterpret_cast<float4*>(&Ws[(kc + k) * 128 + 64 + tx * 4]);
            float xr[8] = {xa.x, xa.y, xa.z, xa.w, xb.x, xb.y, xb.z, xb.w};
            float wc[8] = {wa.x, wa.y, wa.z, wa.w, wb.x, wb.y, wb.z, wb.w};
            #pragma unroll
            for (int r = 0; r < 8; r++)
                #pragma unroll
                for (int c = 0; c < 8; c++)
                    acc[r][c] += xr[r] * wc[c];
        }
    }

    #pragma unroll
    for (int r = 0; r < 8; r++) {
        int grow = row0 + ty * 8 + r;
        if (grow < N) {
            reinterpret_cast<float4*>(Y)[(size_t)grow * 32 + tx] =
                make_float4(acc[r][0], acc[r][1], acc[r][2], acc[r][3]);
            reinterpret_cast<float4*>(Y)[(size_t)grow * 32 + 16 + tx] =
                make_float4(acc[r][4], acc[r][5], acc[r][6], acc[r][7]);
        }
    }
}

// ---------------------------------------------------------------- gather-aggregate
// one wave per node: Y[n] = relu( (sum_{e in CSR[n]} H[col[e]]) * sin_[n] + bias )
__global__ __launch_bounds__(256) void gather_agg(const float* __restrict__ H,
                                                  const int* __restrict__ row_ptr,
                                                  const int* __restrict__ col,
                                                  const float* __restrict__ sin_,
                                                  const float* __restrict__ bias,
                                                  float* __restrict__ Y, int N)
{
    int node = blockIdx.x * 4 + (threadIdx.x >> 6);
    if (node >= N) return;
    int lane = threadIdx.x & 63;
    int beg = row_ptr[node], end = row_ptr[node + 1];
    const float2* H2 = reinterpret_cast<const float2*>(H);
    float2 acc = make_float2(0.f, 0.f);
    int i = beg;
    for (; i + 3 < end; i += 4) {
        int s0 = col[i], s1 = col[i + 1], s2 = col[i + 2], s3 = col[i + 3];
        float2 v0 = H2[(size_t)s0 * 64 + lane];
        float2 v1 = H2[(size_t)s1 * 64 + lane];
        float2 v2 = H2[(size_t)s2 * 64 + lane];
        float2 v3 = H2[(size_t)s3 * 64 + lane];
        acc.x += v0.x + v1.x + v2.x + v3.x;
        acc.y += v0.y + v1.y + v2.y + v3.y;
    }
    for (; i < end; i++) {
        int s = col[i];
        float2 v = H2[(size_t)s * 64 + lane];
        acc.x += v.x; acc.y += v.y;
    }
    float sc = sin_[node];
    float2 b = reinterpret_cast<const float2*>(bias)[lane];
    float2 o;
    o.x = fmaxf(acc.x * sc + b.x, 0.f);
    o.y = fmaxf(acc.y * sc + b.y, 0.f);
    reinterpret_cast<float2*>(Y)[(size_t)node * 64 + lane] = o;
}

// ---------------------------------------------------------------- classifier
__global__ __launch_bounds__(256) void classifier(const float* __restrict__ H,
                                                  const float* __restrict__ Wc,
                                                  const float* __restrict__ bc,
                                                  float* __restrict__ out, int N)
{
    __shared__ float4 Wcs[128];
    for (int i = threadIdx.x; i < 128; i += 256)
        Wcs[i] = reinterpret_cast<const float4*>(Wc)[i];
    __syncthreads();
    int i = blockIdx.x * 256 + threadIdx.x;
    if (i < N) {
        float4 acc = reinterpret_cast<const float4*>(bc)[0];
        const float4* h4 = reinterpret_cast<const float4*>(H) + (size_t)i * 32;
        #pragma unroll
        for (int k4 = 0; k4 < 32; k4++) {
            float4 h = h4[k4];
            float4 w0 = Wcs[k4 * 4 + 0], w1 = Wcs[k4 * 4 + 1];
            float4 w2 = Wcs[k4 * 4 + 2], w3 = Wcs[k4 * 4 + 3];
            acc.x += h.x * w0.x + h.y * w1.x + h.z * w2.x + h.w * w3.x;
            acc.y += h.x * w0.y + h.y * w1.y + h.z * w2.y + h.w * w3.y;
            acc.z += h.x * w0.z + h.y * w1.z + h.z * w2.z + h.w * w3.z;
            acc.w += h.x * w0.w + h.y * w1.w + h.z * w2.w + h.w * w3.w;
        }
        reinterpret_cast<float4*>(out)[i] = acc;
    }
}

// ---------------------------------------------------------------- launch
extern "C" void kernel_launch(void* const* d_in, const int* in_sizes, int n_in,
                              void* d_out, int out_size, void* d_ws, size_t ws_size,
                              hipStream_t stream)
{
    const float* features = (const float*)d_in[0];
    const int*   src      = (const int*)d_in[1];
    const int*   dst      = (const int*)d_in[2];
    const float* W1       = (const float*)d_in[3];
    const float* b1       = (const float*)d_in[4];
    const float* W2       = (const float*)d_in[5];
    const float* b2       = (const float*)d_in[6];
    const float* Wc       = (const float*)d_in[7];
    const float* bc       = (const float*)d_in[8];
    float* out = (float*)d_out;

    char* ws = (char*)d_ws;
    const size_t MB = 1 << 20;
    int*   cnt_out = (int*)(ws + 0 * MB);
    int*   cnt_in  = (int*)(ws + 1 * MB);
    float* sout    = (float*)(ws + 2 * MB);
    float* sin_    = (float*)(ws + 3 * MB);
    int*   row_ptr = (int*)(ws + 4 * MB);
    int*   cursor  = (int*)(ws + 5 * MB);
    int*   bsum    = (int*)(ws + 5 * MB + 512 * 1024);
    int*   bofs    = (int*)(ws + 5 * MB + 768 * 1024);
    int*   col     = (int*)(ws + 6 * MB);
    float* bufA    = (float*)(ws + 13 * MB);
    float* bufB    = (float*)(ws + 13 * MB + (size_t)N_NODES * F * 4);

    const int N = N_NODES, E = N_EDGES;
    const int NBLK = (N + SCAN_B - 1) / SCAN_B;          // 391
    const int EBLK = (E + 256 * EPT - 1) / (256 * EPT);  // 782
    const int GBLK = (N + 127) / 128;                    // 782

    // ---- CSR build + degree norms
    hipMemsetAsync(cnt_out, 0, N * sizeof(int), stream);
    hipMemsetAsync(cnt_in, 0, N * sizeof(int), stream);
    deg_kernel<<<EBLK, 256, 0, stream>>>(src, dst, cnt_out, cnt_in, E);
    rsqrt_kernel<<<(N + 255) / 256, 256, 0, stream>>>(cnt_out, cnt_in, sout, sin_, N);
    scan_partial<<<NBLK, SCAN_B, 0, stream>>>(cnt_in, bsum, N);
    scan_bsums<<<1, 512, 0, stream>>>(bsum, bofs, NBLK);
    scan_final<<<NBLK, SCAN_B, 0, stream>>>(cnt_in, bofs, row_ptr, cursor, N, E);
    fill_kernel<<<EBLK, 256, 0, stream>>>(src, dst, cursor, col, E);

    // ---- layer 1
    gemm128<<<GBLK, 256, 0, stream>>>(features, sout, W1, bufA, N);
    gather_agg<<<(N + 3) / 4, 256, 0, stream>>>(bufA, row_ptr, col, sin_, b1, bufB, N);

    // ---- layer 2
    gemm128<<<GBLK, 256, 0, stream>>>(bufB, sout, W2, bufA, N);
    gather_agg<<<(N + 3) / 4, 256, 0, stream>>>(bufA, row_ptr, col, sin_, b2, bufB, N);

    // ---- classifier
    classifier<<<(N + 255) / 256, 256, 0, stream>>>(bufB, Wc, bc, out, N);
}

// Round 5
// 572.560 us; speedup vs baseline: 10.2934x; 1.3579x over previous
//
#include <hip/hip_runtime.h>
#include <math.h>

#define N_NODES 100000
#define N_EDGES 1600000
#define F 128
#define NBUK 196        // ceil(N_NODES / 512)
#define BSH 9           // bucket = node >> 9  (512 nodes per bucket)
#define BSZ 512

// ---------------------------------------------------------------- K1: bucket totals
// LDS hist of dst>>9 and src>>9; merge via ~77K device atomics (vs 3.2M before)
__global__ __launch_bounds__(256) void hist_buckets(const int* __restrict__ src,
                                                    const int* __restrict__ dst,
                                                    int* __restrict__ totD,
                                                    int* __restrict__ totS)
{
    __shared__ int hd[NBUK], hs[NBUK];
    const int tid = threadIdx.x;
    if (tid < NBUK) { hd[tid] = 0; hs[tid] = 0; }
    __syncthreads();
    const int nt = gridDim.x * 256;
    const int n4 = N_EDGES / 4;
    for (int i = blockIdx.x * 256 + tid; i < n4; i += nt) {
        int4 d = reinterpret_cast<const int4*>(dst)[i];
        int4 s = reinterpret_cast<const int4*>(src)[i];
        atomicAdd(&hd[d.x >> BSH], 1); atomicAdd(&hd[d.y >> BSH], 1);
        atomicAdd(&hd[d.z >> BSH], 1); atomicAdd(&hd[d.w >> BSH], 1);
        atomicAdd(&hs[s.x >> BSH], 1); atomicAdd(&hs[s.y >> BSH], 1);
        atomicAdd(&hs[s.z >> BSH], 1); atomicAdd(&hs[s.w >> BSH], 1);
    }
    __syncthreads();
    if (tid < NBUK) {
        if (hd[tid]) atomicAdd(&totD[tid], hd[tid]);
        if (hs[tid]) atomicAdd(&totS[tid], hs[tid]);
    }
}

// ---------------------------------------------------------------- K2: scan totals
__global__ __launch_bounds__(256) void scan_buckets(const int* __restrict__ totD,
                                                    const int* __restrict__ totS,
                                                    int* __restrict__ baseD,
                                                    int* __restrict__ baseS,
                                                    int* __restrict__ curD,
                                                    int* __restrict__ curS)
{
    __shared__ int sd[256], ss[256];
    const int t = threadIdx.x;
    int vd = (t < NBUK) ? totD[t] : 0;
    int vs = (t < NBUK) ? totS[t] : 0;
    sd[t] = vd; ss[t] = vs;
    __syncthreads();
    for (int off = 1; off < 256; off <<= 1) {
        int ud = (t >= off) ? sd[t - off] : 0;
        int us = (t >= off) ? ss[t - off] : 0;
        __syncthreads();
        sd[t] += ud; ss[t] += us;
        __syncthreads();
    }
    if (t < NBUK) {
        baseD[t] = sd[t] - vd; curD[t] = sd[t] - vd;
        baseS[t] = ss[t] - vs; curS[t] = ss[t] - vs;
    }
    if (t == NBUK - 1) { baseD[NBUK] = sd[t]; baseS[NBUK] = ss[t]; }
}

// ---------------------------------------------------------------- K3: partition
// per-block LDS hist -> one reservation atomic per (block,bin) -> scatter with
// ~40-element contiguous runs per bin (L2-coalesced full-line writebacks)
__global__ __launch_bounds__(512) void partition(const int* __restrict__ src,
                                                 const int* __restrict__ dst,
                                                 int* __restrict__ curD,
                                                 int* __restrict__ curS,
                                                 int2* __restrict__ bukD,
                                                 int* __restrict__ bukS)
{
    __shared__ int hd[NBUK], hs[NBUK], bd[NBUK], bs[NBUK], cd[NBUK], cs[NBUK];
    const int tid = threadIdx.x;
    const int chunk = (N_EDGES + gridDim.x - 1) / gridDim.x;
    const int beg = blockIdx.x * chunk;
    const int end = min(beg + chunk, N_EDGES);
    if (tid < NBUK) { hd[tid] = 0; hs[tid] = 0; cd[tid] = 0; cs[tid] = 0; }
    __syncthreads();
    for (int e = beg + tid; e < end; e += 512) {
        atomicAdd(&hd[dst[e] >> BSH], 1);
        atomicAdd(&hs[src[e] >> BSH], 1);
    }
    __syncthreads();
    if (tid < NBUK) {
        bd[tid] = hd[tid] ? atomicAdd(&curD[tid], hd[tid]) : 0;
        bs[tid] = hs[tid] ? atomicAdd(&curS[tid], hs[tid]) : 0;
    }
    __syncthreads();
    for (int e = beg + tid; e < end; e += 512) {
        int d = dst[e], s = src[e];
        int bin = d >> BSH;
        int r = atomicAdd(&cd[bin], 1);
        bukD[bd[bin] + r] = make_int2(d, s);
        int bin2 = s >> BSH;
        int r2 = atomicAdd(&cs[bin2], 1);
        bukS[bs[bin2] + r2] = s;
    }
}

// ---------------------------------------------------------------- K4: per-bucket CSR
// one block per bucket: LDS count -> LDS scan -> row_ptr/sin_ coalesced,
// col scattered densely within the bucket's own region (full lines)
__global__ __launch_bounds__(512) void csr_bucket(const int2* __restrict__ bukD,
                                                  const int* __restrict__ baseD,
                                                  int* __restrict__ row_ptr,
                                                  float* __restrict__ sin_,
                                                  int* __restrict__ col)
{
    __shared__ int h[BSZ], sc[BSZ], cur[BSZ];
    const int tid = threadIdx.x;
    const int n0 = blockIdx.x << BSH;
    const int lo = baseD[blockIdx.x], hi = baseD[blockIdx.x + 1];
    h[tid] = 0;
    __syncthreads();
    for (int i = lo + tid; i < hi; i += 512)
        atomicAdd(&h[bukD[i].x - n0], 1);
    __syncthreads();
    int own = h[tid];
    sc[tid] = own;
    __syncthreads();
    for (int off = 1; off < 512; off <<= 1) {
        int u = (tid >= off) ? sc[tid - off] : 0;
        __syncthreads();
        sc[tid] += u;
        __syncthreads();
    }
    int ex = sc[tid] - own;          // exclusive prefix within bucket
    cur[tid] = ex;
    int node = n0 + tid;
    if (node <= N_NODES) row_ptr[node] = lo + ex;
    if (node < N_NODES)  sin_[node] = rsqrtf((float)max(own, 1));
    __syncthreads();
    for (int i = lo + tid; i < hi; i += 512) {
        int2 p = bukD[i];
        int r = atomicAdd(&cur[p.x - n0], 1);
        col[lo + r] = p.y;
    }
}

// ---------------------------------------------------------------- K5: out-degree
__global__ __launch_bounds__(512) void deg_bucket(const int* __restrict__ bukS,
                                                  const int* __restrict__ baseS,
                                                  float* __restrict__ sout)
{
    __shared__ int h[BSZ];
    const int tid = threadIdx.x;
    const int n0 = blockIdx.x << BSH;
    const int lo = baseS[blockIdx.x], hi = baseS[blockIdx.x + 1];
    h[tid] = 0;
    __syncthreads();
    for (int i = lo + tid; i < hi; i += 512)
        atomicAdd(&h[bukS[i] - n0], 1);
    __syncthreads();
    int node = n0 + tid;
    if (node < N_NODES) sout[node] = rsqrtf((float)max(h[tid], 1));
}

// ---------------------------------------------------------------- GEMM
// Y[N,128] = diag(srow) * X[N,128] @ W[128,128]   (fp32, vector ALU)
// 256 thr, tile 128x128, 8x8 micro-tile, W fully LDS-resident
__global__ __launch_bounds__(256) void gemm128(const float* __restrict__ X,
                                               const float* __restrict__ srow,
                                               const float* __restrict__ W,
                                               float* __restrict__ Y, int N)
{
    __shared__ float Ws[128 * 128];   // [k][n], 64 KB
    __shared__ float Xs[32 * 128];    // [k][m], 16 KB
    const int tid = threadIdx.x;
    const int tx = tid & 15;
    const int ty = tid >> 4;
    const int row0 = blockIdx.x * 128;

    for (int i = tid; i < 4096; i += 256)
        reinterpret_cast<float4*>(Ws)[i] = reinterpret_cast<const float4*>(W)[i];

    float acc[8][8];
    #pragma unroll
    for (int r = 0; r < 8; r++)
        #pragma unroll
        for (int c = 0; c < 8; c++) acc[r][c] = 0.f;

    const int m = tid & 127;
    const int half = tid >> 7;
    const int grow_s = row0 + m;
    const bool ok = grow_s < N;
    float s = ok ? srow[grow_s] : 0.f;

    for (int kc = 0; kc < 128; kc += 32) {
        __syncthreads();
        #pragma unroll
        for (int j = 0; j < 4; j++) {
            int k4 = half * 4 + j;
            float4 v = ok ? reinterpret_cast<const float4*>(X)[(size_t)grow_s * 32 + (kc >> 2) + k4]
                          : make_float4(0.f, 0.f, 0.f, 0.f);
            int kb = k4 * 4;
            Xs[(kb + 0) * 128 + m] = v.x * s;
            Xs[(kb + 1) * 128 + m] = v.y * s;
            Xs[(kb + 2) * 128 + m] = v.z * s;
            Xs[(kb + 3) * 128 + m] = v.w * s;
        }
        __syncthreads();

        #pragma unroll
        for (int k = 0; k < 32; k++) {
            float4 xa = *reinterpret_cast<float4*>(&Xs[k * 128 + ty * 8]);
            float4 xb = *reinterpret_cast<float4*>(&Xs[k * 128 + ty * 8 + 4]);
            float4 wa = *reinterpret_cast<float4*>(&Ws[(kc + k) * 128 + tx * 4]);
            float4 wb = *reinterpret_cast<float4*>(&Ws[(kc + k) * 128 + 64 + tx * 4]);
            float xr[8] = {xa.x, xa.y, xa.z, xa.w, xb.x, xb.y, xb.z, xb.w};
            float wc[8] = {wa.x, wa.y, wa.z, wa.w, wb.x, wb.y, wb.z, wb.w};
            #pragma unroll
            for (int r = 0; r < 8; r++)
                #pragma unroll
                for (int c = 0; c < 8; c++)
                    acc[r][c] += xr[r] * wc[c];
        }
    }

    #pragma unroll
    for (int r = 0; r < 8; r++) {
        int grow = row0 + ty * 8 + r;
        if (grow < N) {
            reinterpret_cast<float4*>(Y)[(size_t)grow * 32 + tx] =
                make_float4(acc[r][0], acc[r][1], acc[r][2], acc[r][3]);
            reinterpret_cast<float4*>(Y)[(size_t)grow * 32 + 16 + tx] =
                make_float4(acc[r][4], acc[r][5], acc[r][6], acc[r][7]);
        }
    }
}

// ---------------------------------------------------------------- gather-aggregate
__global__ __launch_bounds__(256) void gather_agg(const float* __restrict__ H,
                                                  const int* __restrict__ row_ptr,
                                                  const int* __restrict__ col,
                                                  const float* __restrict__ sin_,
                                                  const float* __restrict__ bias,
                                                  float* __restrict__ Y, int N)
{
    int node = blockIdx.x * 4 + (threadIdx.x >> 6);
    if (node >= N) return;
    int lane = threadIdx.x & 63;
    int beg = row_ptr[node], end = row_ptr[node + 1];
    const float2* H2 = reinterpret_cast<const float2*>(H);
    float2 acc = make_float2(0.f, 0.f);
    int i = beg;
    for (; i + 3 < end; i += 4) {
        int s0 = col[i], s1 = col[i + 1], s2 = col[i + 2], s3 = col[i + 3];
        float2 v0 = H2[(size_t)s0 * 64 + lane];
        float2 v1 = H2[(size_t)s1 * 64 + lane];
        float2 v2 = H2[(size_t)s2 * 64 + lane];
        float2 v3 = H2[(size_t)s3 * 64 + lane];
        acc.x += v0.x + v1.x + v2.x + v3.x;
        acc.y += v0.y + v1.y + v2.y + v3.y;
    }
    for (; i < end; i++) {
        int s = col[i];
        float2 v = H2[(size_t)s * 64 + lane];
        acc.x += v.x; acc.y += v.y;
    }
    float sc = sin_[node];
    float2 b = reinterpret_cast<const float2*>(bias)[lane];
    float2 o;
    o.x = fmaxf(acc.x * sc + b.x, 0.f);
    o.y = fmaxf(acc.y * sc + b.y, 0.f);
    reinterpret_cast<float2*>(Y)[(size_t)node * 64 + lane] = o;
}

// ---------------------------------------------------------------- classifier
__global__ __launch_bounds__(256) void classifier(const float* __restrict__ H,
                                                  const float* __restrict__ Wc,
                                                  const float* __restrict__ bc,
                                                  float* __restrict__ out, int N)
{
    __shared__ float4 Wcs[128];
    for (int i = threadIdx.x; i < 128; i += 256)
        Wcs[i] = reinterpret_cast<const float4*>(Wc)[i];
    __syncthreads();
    int i = blockIdx.x * 256 + threadIdx.x;
    if (i < N) {
        float4 acc = reinterpret_cast<const float4*>(bc)[0];
        const float4* h4 = reinterpret_cast<const float4*>(H) + (size_t)i * 32;
        #pragma unroll
        for (int k4 = 0; k4 < 32; k4++) {
            float4 h = h4[k4];
            float4 w0 = Wcs[k4 * 4 + 0], w1 = Wcs[k4 * 4 + 1];
            float4 w2 = Wcs[k4 * 4 + 2], w3 = Wcs[k4 * 4 + 3];
            acc.x += h.x * w0.x + h.y * w1.x + h.z * w2.x + h.w * w3.x;
            acc.y += h.x * w0.y + h.y * w1.y + h.z * w2.y + h.w * w3.y;
            acc.z += h.x * w0.z + h.y * w1.z + h.z * w2.z + h.w * w3.z;
            acc.w += h.x * w0.w + h.y * w1.w + h.z * w2.w + h.w * w3.w;
        }
        reinterpret_cast<float4*>(out)[i] = acc;
    }
}

// ---------------------------------------------------------------- launch
extern "C" void kernel_launch(void* const* d_in, const int* in_sizes, int n_in,
                              void* d_out, int out_size, void* d_ws, size_t ws_size,
                              hipStream_t stream)
{
    const float* features = (const float*)d_in[0];
    const int*   src      = (const int*)d_in[1];
    const int*   dst      = (const int*)d_in[2];
    const float* W1       = (const float*)d_in[3];
    const float* b1       = (const float*)d_in[4];
    const float* W2       = (const float*)d_in[5];
    const float* b2       = (const float*)d_in[6];
    const float* Wc       = (const float*)d_in[7];
    const float* bc       = (const float*)d_in[8];
    float* out = (float*)d_out;

    char* ws = (char*)d_ws;
    const size_t MB = 1 << 20;
    int* totD  = (int*)(ws + 0);
    int* totS  = (int*)(ws + 1024);
    int* baseD = (int*)(ws + 2048);
    int* baseS = (int*)(ws + 3072);
    int* curD  = (int*)(ws + 4096);
    int* curS  = (int*)(ws + 5120);
    float* sout    = (float*)(ws + 1 * MB);      // N floats
    float* sin_    = (float*)(ws + 2 * MB);      // N floats
    int*   row_ptr = (int*)(ws + 3 * MB);        // N+1 ints
    int*   col     = (int*)(ws + 4 * MB);        // E ints (6.4 MB)
    int2*  bukD    = (int2*)(ws + 11 * MB);      // E pairs (12.8 MB) — dead after csr_bucket
    int*   bukS    = (int*)(ws + 24 * MB);       // E ints (6.4 MB)  — dead after deg_bucket
    float* bufB    = (float*)(ws + 11 * MB);     // [N,128] overlaps bukD/bukS (safe: written later)
    float* bufA    = (float*)(ws + 63 * MB);     // [N,128]

    const int N = N_NODES, E = N_EDGES;
    const int GBLK = (N + 127) / 128;            // 782

    // ---- CSR build + degree norms (bucket counting sort; no per-edge device atomics)
    hipMemsetAsync(ws, 0, 2048, stream);         // totD, totS
    hist_buckets<<<392, 256, 0, stream>>>(src, dst, totD, totS);
    scan_buckets<<<1, 256, 0, stream>>>(totD, totS, baseD, baseS, curD, curS);
    partition<<<NBUK, 512, 0, stream>>>(src, dst, curD, curS, bukD, bukS);
    csr_bucket<<<NBUK, 512, 0, stream>>>(bukD, baseD, row_ptr, sin_, col);
    deg_bucket<<<NBUK, 512, 0, stream>>>(bukS, baseS, sout);

    // ---- layer 1
    gemm128<<<GBLK, 256, 0, stream>>>(features, sout, W1, bufA, N);
    gather_agg<<<(N + 3) / 4, 256, 0, stream>>>(bufA, row_ptr, col, sin_, b1, bufB, N);

    // ---- layer 2
    gemm128<<<GBLK, 256, 0, stream>>>(bufB, sout, W2, bufA, N);
    gather_agg<<<(N + 3) / 4, 256, 0, stream>>>(bufA, row_ptr, col, sin_, b2, bufB, N);

    // ---- classifier
    classifier<<<(N + 255) / 256, 256, 0, stream>>>(bufB, Wc, bc, out, N);
}

// Round 6
// 486.763 us; speedup vs baseline: 12.1078x; 1.1763x over previous
//
#include <hip/hip_runtime.h>
#include <hip/hip_fp16.h>
#include <math.h>

#define N_NODES 100000
#define N_EDGES 1600000
#define F 128
#define NBUK 196        // ceil(N_NODES / 512)
#define BSH 9           // bucket = node >> 9  (512 nodes per bucket)
#define BSZ 512

// ---------------------------------------------------------------- K1: bucket totals
__global__ __launch_bounds__(256) void hist_buckets(const int* __restrict__ src,
                                                    const int* __restrict__ dst,
                                                    int* __restrict__ totD,
                                                    int* __restrict__ totS)
{
    __shared__ int hd[NBUK], hs[NBUK];
    const int tid = threadIdx.x;
    if (tid < NBUK) { hd[tid] = 0; hs[tid] = 0; }
    __syncthreads();
    const int nt = gridDim.x * 256;
    const int n4 = N_EDGES / 4;
    for (int i = blockIdx.x * 256 + tid; i < n4; i += nt) {
        int4 d = reinterpret_cast<const int4*>(dst)[i];
        int4 s = reinterpret_cast<const int4*>(src)[i];
        atomicAdd(&hd[d.x >> BSH], 1); atomicAdd(&hd[d.y >> BSH], 1);
        atomicAdd(&hd[d.z >> BSH], 1); atomicAdd(&hd[d.w >> BSH], 1);
        atomicAdd(&hs[s.x >> BSH], 1); atomicAdd(&hs[s.y >> BSH], 1);
        atomicAdd(&hs[s.z >> BSH], 1); atomicAdd(&hs[s.w >> BSH], 1);
    }
    __syncthreads();
    if (tid < NBUK) {
        if (hd[tid]) atomicAdd(&totD[tid], hd[tid]);
        if (hs[tid]) atomicAdd(&totS[tid], hs[tid]);
    }
}

// ---------------------------------------------------------------- K2: scan totals
__global__ __launch_bounds__(256) void scan_buckets(const int* __restrict__ totD,
                                                    const int* __restrict__ totS,
                                                    int* __restrict__ baseD,
                                                    int* __restrict__ baseS,
                                                    int* __restrict__ curD,
                                                    int* __restrict__ curS)
{
    __shared__ int sd[256], ss[256];
    const int t = threadIdx.x;
    int vd = (t < NBUK) ? totD[t] : 0;
    int vs = (t < NBUK) ? totS[t] : 0;
    sd[t] = vd; ss[t] = vs;
    __syncthreads();
    for (int off = 1; off < 256; off <<= 1) {
        int ud = (t >= off) ? sd[t - off] : 0;
        int us = (t >= off) ? ss[t - off] : 0;
        __syncthreads();
        sd[t] += ud; ss[t] += us;
        __syncthreads();
    }
    if (t < NBUK) {
        baseD[t] = sd[t] - vd; curD[t] = sd[t] - vd;
        baseS[t] = ss[t] - vs; curS[t] = ss[t] - vs;
    }
    if (t == NBUK - 1) { baseD[NBUK] = sd[t]; baseS[NBUK] = ss[t]; }
}

// ---------------------------------------------------------------- K3: partition
__global__ __launch_bounds__(512) void partition(const int* __restrict__ src,
                                                 const int* __restrict__ dst,
                                                 int* __restrict__ curD,
                                                 int* __restrict__ curS,
                                                 int2* __restrict__ bukD,
                                                 int* __restrict__ bukS)
{
    __shared__ int hd[NBUK], hs[NBUK], bd[NBUK], bs[NBUK], cd[NBUK], cs[NBUK];
    const int tid = threadIdx.x;
    const int chunk = (N_EDGES + gridDim.x - 1) / gridDim.x;
    const int beg = blockIdx.x * chunk;
    const int end = min(beg + chunk, N_EDGES);
    if (tid < NBUK) { hd[tid] = 0; hs[tid] = 0; cd[tid] = 0; cs[tid] = 0; }
    __syncthreads();
    for (int e = beg + tid; e < end; e += 512) {
        atomicAdd(&hd[dst[e] >> BSH], 1);
        atomicAdd(&hs[src[e] >> BSH], 1);
    }
    __syncthreads();
    if (tid < NBUK) {
        bd[tid] = hd[tid] ? atomicAdd(&curD[tid], hd[tid]) : 0;
        bs[tid] = hs[tid] ? atomicAdd(&curS[tid], hs[tid]) : 0;
    }
    __syncthreads();
    for (int e = beg + tid; e < end; e += 512) {
        int d = dst[e], s = src[e];
        int bin = d >> BSH;
        int r = atomicAdd(&cd[bin], 1);
        bukD[bd[bin] + r] = make_int2(d, s);
        int bin2 = s >> BSH;
        int r2 = atomicAdd(&cs[bin2], 1);
        bukS[bs[bin2] + r2] = s;
    }
}

// ---------------------------------------------------------------- K4: per-bucket CSR
__global__ __launch_bounds__(512) void csr_bucket(const int2* __restrict__ bukD,
                                                  const int* __restrict__ baseD,
                                                  int* __restrict__ row_ptr,
                                                  float* __restrict__ sin_,
                                                  int* __restrict__ col)
{
    __shared__ int h[BSZ], sc[BSZ], cur[BSZ];
    const int tid = threadIdx.x;
    const int n0 = blockIdx.x << BSH;
    const int lo = baseD[blockIdx.x], hi = baseD[blockIdx.x + 1];
    h[tid] = 0;
    __syncthreads();
    for (int i = lo + tid; i < hi; i += 512)
        atomicAdd(&h[bukD[i].x - n0], 1);
    __syncthreads();
    int own = h[tid];
    sc[tid] = own;
    __syncthreads();
    for (int off = 1; off < 512; off <<= 1) {
        int u = (tid >= off) ? sc[tid - off] : 0;
        __syncthreads();
        sc[tid] += u;
        __syncthreads();
    }
    int ex = sc[tid] - own;
    cur[tid] = ex;
    int node = n0 + tid;
    if (node <= N_NODES) row_ptr[node] = lo + ex;
    if (node < N_NODES)  sin_[node] = rsqrtf((float)max(own, 1));
    __syncthreads();
    for (int i = lo + tid; i < hi; i += 512) {
        int2 p = bukD[i];
        int r = atomicAdd(&cur[p.x - n0], 1);
        col[lo + r] = p.y;
    }
}

// ---------------------------------------------------------------- K5: out-degree
__global__ __launch_bounds__(512) void deg_bucket(const int* __restrict__ bukS,
                                                  const int* __restrict__ baseS,
                                                  float* __restrict__ sout)
{
    __shared__ int h[BSZ];
    const int tid = threadIdx.x;
    const int n0 = blockIdx.x << BSH;
    const int lo = baseS[blockIdx.x], hi = baseS[blockIdx.x + 1];
    h[tid] = 0;
    __syncthreads();
    for (int i = lo + tid; i < hi; i += 512)
        atomicAdd(&h[bukS[i] - n0], 1);
    __syncthreads();
    int node = n0 + tid;
    if (node < N_NODES) sout[node] = rsqrtf((float)max(h[tid], 1));
}

// ---------------------------------------------------------------- GEMM (fp16 out)
// Yh[N,128] = fp16( diag(srow) * X[N,128] @ W[128,128] )   (fp32 accumulate)
__global__ __launch_bounds__(256) void gemm128(const float* __restrict__ X,
                                               const float* __restrict__ srow,
                                               const float* __restrict__ W,
                                               __half* __restrict__ Yh, int N)
{
    __shared__ float Ws[128 * 128];   // [k][n], 64 KB
    __shared__ float Xs[32 * 128];    // [k][m], 16 KB
    const int tid = threadIdx.x;
    const int tx = tid & 15;
    const int ty = tid >> 4;
    const int row0 = blockIdx.x * 128;

    for (int i = tid; i < 4096; i += 256)
        reinterpret_cast<float4*>(Ws)[i] = reinterpret_cast<const float4*>(W)[i];

    float acc[8][8];
    #pragma unroll
    for (int r = 0; r < 8; r++)
        #pragma unroll
        for (int c = 0; c < 8; c++) acc[r][c] = 0.f;

    const int m = tid & 127;
    const int half_ = tid >> 7;
    const int grow_s = row0 + m;
    const bool ok = grow_s < N;
    float s = ok ? srow[grow_s] : 0.f;

    for (int kc = 0; kc < 128; kc += 32) {
        __syncthreads();
        #pragma unroll
        for (int j = 0; j < 4; j++) {
            int k4 = half_ * 4 + j;
            float4 v = ok ? reinterpret_cast<const float4*>(X)[(size_t)grow_s * 32 + (kc >> 2) + k4]
                          : make_float4(0.f, 0.f, 0.f, 0.f);
            int kb = k4 * 4;
            Xs[(kb + 0) * 128 + m] = v.x * s;
            Xs[(kb + 1) * 128 + m] = v.y * s;
            Xs[(kb + 2) * 128 + m] = v.z * s;
            Xs[(kb + 3) * 128 + m] = v.w * s;
        }
        __syncthreads();

        #pragma unroll
        for (int k = 0; k < 32; k++) {
            float4 xa = *reinterpret_cast<float4*>(&Xs[k * 128 + ty * 8]);
            float4 xb = *reinterpret_cast<float4*>(&Xs[k * 128 + ty * 8 + 4]);
            float4 wa = *reinterpret_cast<float4*>(&Ws[(kc + k) * 128 + tx * 4]);
            float4 wb = *reinterpret_cast<float4*>(&Ws[(kc + k) * 128 + 64 + tx * 4]);
            float xr[8] = {xa.x, xa.y, xa.z, xa.w, xb.x, xb.y, xb.z, xb.w};
            float wc[8] = {wa.x, wa.y, wa.z, wa.w, wb.x, wb.y, wb.z, wb.w};
            #pragma unroll
            for (int r = 0; r < 8; r++)
                #pragma unroll
                for (int c = 0; c < 8; c++)
                    acc[r][c] += xr[r] * wc[c];
        }
    }

    // store fp16: row = 128 halves = 32 int2; cols tx*4..+3 -> int2 idx tx,
    // cols 64+tx*4..+3 -> int2 idx 16+tx (8B stores, coalesced)
    #pragma unroll
    for (int r = 0; r < 8; r++) {
        int grow = row0 + ty * 8 + r;
        if (grow < N) {
            union { __half2 h2[2]; int2 i2; } pa, pb;
            pa.h2[0] = __floats2half2_rn(acc[r][0], acc[r][1]);
            pa.h2[1] = __floats2half2_rn(acc[r][2], acc[r][3]);
            pb.h2[0] = __floats2half2_rn(acc[r][4], acc[r][5]);
            pb.h2[1] = __floats2half2_rn(acc[r][6], acc[r][7]);
            reinterpret_cast<int2*>(Yh)[(size_t)grow * 32 + tx] = pa.i2;
            reinterpret_cast<int2*>(Yh)[(size_t)grow * 32 + 16 + tx] = pb.i2;
        }
    }
}

// ---------------------------------------------------------------- gather-aggregate
// one wave per node, fp16 messages (256 B/row = 2 lines), fp32 accumulate:
// Y[n] = relu( (sum_{e in CSR[n]} Hh[col[e]]) * sin_[n] + bias )
__global__ __launch_bounds__(256) void gather_agg(const __half* __restrict__ Hh,
                                                  const int* __restrict__ row_ptr,
                                                  const int* __restrict__ col,
                                                  const float* __restrict__ sin_,
                                                  const float* __restrict__ bias,
                                                  float* __restrict__ Y, int N)
{
    int node = blockIdx.x * 4 + (threadIdx.x >> 6);
    if (node >= N) return;
    int lane = threadIdx.x & 63;
    int beg = row_ptr[node], end = row_ptr[node + 1];
    const __half2* H2 = reinterpret_cast<const __half2*>(Hh);   // 64 half2 per row
    float2 acc0 = make_float2(0.f, 0.f);
    float2 acc1 = make_float2(0.f, 0.f);
    int i = beg;
    for (; i + 3 < end; i += 4) {
        int s0 = col[i], s1 = col[i + 1], s2 = col[i + 2], s3 = col[i + 3];
        __half2 v0 = H2[(size_t)s0 * 64 + lane];
        __half2 v1 = H2[(size_t)s1 * 64 + lane];
        __half2 v2 = H2[(size_t)s2 * 64 + lane];
        __half2 v3 = H2[(size_t)s3 * 64 + lane];
        float2 f0 = __half22float2(v0), f1 = __half22float2(v1);
        float2 f2 = __half22float2(v2), f3 = __half22float2(v3);
        acc0.x += f0.x + f1.x; acc0.y += f0.y + f1.y;
        acc1.x += f2.x + f3.x; acc1.y += f2.y + f3.y;
    }
    for (; i < end; i++) {
        int s = col[i];
        float2 f = __half22float2(H2[(size_t)s * 64 + lane]);
        acc0.x += f.x; acc0.y += f.y;
    }
    float sc = sin_[node];
    float2 b = reinterpret_cast<const float2*>(bias)[lane];
    float2 o;
    o.x = fmaxf((acc0.x + acc1.x) * sc + b.x, 0.f);
    o.y = fmaxf((acc0.y + acc1.y) * sc + b.y, 0.f);
    reinterpret_cast<float2*>(Y)[(size_t)node * 64 + lane] = o;
}

// ---------------------------------------------------------------- classifier
__global__ __launch_bounds__(256) void classifier(const float* __restrict__ H,
                                                  const float* __restrict__ Wc,
                                                  const float* __restrict__ bc,
                                                  float* __restrict__ out, int N)
{
    __shared__ float4 Wcs[128];
    for (int i = threadIdx.x; i < 128; i += 256)
        Wcs[i] = reinterpret_cast<const float4*>(Wc)[i];
    __syncthreads();
    int i = blockIdx.x * 256 + threadIdx.x;
    if (i < N) {
        float4 acc = reinterpret_cast<const float4*>(bc)[0];
        const float4* h4 = reinterpret_cast<const float4*>(H) + (size_t)i * 32;
        #pragma unroll
        for (int k4 = 0; k4 < 32; k4++) {
            float4 h = h4[k4];
            float4 w0 = Wcs[k4 * 4 + 0], w1 = Wcs[k4 * 4 + 1];
            float4 w2 = Wcs[k4 * 4 + 2], w3 = Wcs[k4 * 4 + 3];
            acc.x += h.x * w0.x + h.y * w1.x + h.z * w2.x + h.w * w3.x;
            acc.y += h.x * w0.y + h.y * w1.y + h.z * w2.y + h.w * w3.y;
            acc.z += h.x * w0.z + h.y * w1.z + h.z * w2.z + h.w * w3.z;
            acc.w += h.x * w0.w + h.y * w1.w + h.z * w2.w + h.w * w3.w;
        }
        reinterpret_cast<float4*>(out)[i] = acc;
    }
}

// ---------------------------------------------------------------- launch
extern "C" void kernel_launch(void* const* d_in, const int* in_sizes, int n_in,
                              void* d_out, int out_size, void* d_ws, size_t ws_size,
                              hipStream_t stream)
{
    const float* features = (const float*)d_in[0];
    const int*   src      = (const int*)d_in[1];
    const int*   dst      = (const int*)d_in[2];
    const float* W1       = (const float*)d_in[3];
    const float* b1       = (const float*)d_in[4];
    const float* W2       = (const float*)d_in[5];
    const float* b2       = (const float*)d_in[6];
    const float* Wc       = (const float*)d_in[7];
    const float* bc       = (const float*)d_in[8];
    float* out = (float*)d_out;

    char* ws = (char*)d_ws;
    const size_t MB = 1 << 20;
    int* totD  = (int*)(ws + 0);
    int* totS  = (int*)(ws + 1024);
    int* baseD = (int*)(ws + 2048);
    int* baseS = (int*)(ws + 3072);
    int* curD  = (int*)(ws + 4096);
    int* curS  = (int*)(ws + 5120);
    float* sout    = (float*)(ws + 1 * MB);      // N floats
    float* sin_    = (float*)(ws + 2 * MB);      // N floats
    int*   row_ptr = (int*)(ws + 3 * MB);        // N+1 ints
    int*   col     = (int*)(ws + 4 * MB);        // E ints (6.4 MB)
    int2*  bukD    = (int2*)(ws + 11 * MB);      // E pairs (12.8 MB) — dead after csr_bucket
    int*   bukS    = (int*)(ws + 24 * MB);       // E ints (6.4 MB)  — dead after deg_bucket
    __half* hH     = (__half*)(ws + 32 * MB);    // [N,128] fp16 messages (25.6 MB)
    float* gF      = (float*)(ws + 60 * MB);     // [N,128] fp32 gather out (51.2 MB)

    const int N = N_NODES;
    const int GBLK = (N + 127) / 128;            // 782

    // ---- CSR build + degree norms (bucket counting sort)
    hipMemsetAsync(ws, 0, 2048, stream);         // totD, totS
    hist_buckets<<<392, 256, 0, stream>>>(src, dst, totD, totS);
    scan_buckets<<<1, 256, 0, stream>>>(totD, totS, baseD, baseS, curD, curS);
    partition<<<NBUK, 512, 0, stream>>>(src, dst, curD, curS, bukD, bukS);
    csr_bucket<<<NBUK, 512, 0, stream>>>(bukD, baseD, row_ptr, sin_, col);
    deg_bucket<<<NBUK, 512, 0, stream>>>(bukS, baseS, sout);

    // ---- layer 1
    gemm128<<<GBLK, 256, 0, stream>>>(features, sout, W1, hH, N);
    gather_agg<<<(N + 3) / 4, 256, 0, stream>>>(hH, row_ptr, col, sin_, b1, gF, N);

    // ---- layer 2
    gemm128<<<GBLK, 256, 0, stream>>>(gF, sout, W2, hH, N);
    gather_agg<<<(N + 3) / 4, 256, 0, stream>>>(hH, row_ptr, col, sin_, b2, gF, N);

    // ---- classifier
    classifier<<<(N + 255) / 256, 256, 0, stream>>>(gF, Wc, bc, out, N);
}

// Round 8
// 377.677 us; speedup vs baseline: 15.6049x; 1.2888x over previous
//
#include <hip/hip_runtime.h>
#include <hip/hip_fp16.h>
#include <math.h>

#define N_NODES 100000
#define N_EDGES 1600000
#define F 128
#define NBUK 196        // ceil(N_NODES / 512)
#define BSH 9           // bucket = node >> 9  (512 nodes per bucket)
#define BSZ 512

typedef _Float16 half8 __attribute__((ext_vector_type(8)));
typedef float    f32x4 __attribute__((ext_vector_type(4)));

// ---------------------------------------------------------------- K1: bucket totals
__global__ __launch_bounds__(256) void hist_buckets(const int* __restrict__ src,
                                                    const int* __restrict__ dst,
                                                    int* __restrict__ totD,
                                                    int* __restrict__ totS)
{
    __shared__ int hd[NBUK], hs[NBUK];
    const int tid = threadIdx.x;
    if (tid < NBUK) { hd[tid] = 0; hs[tid] = 0; }
    __syncthreads();
    const int nt = gridDim.x * 256;
    const int n4 = N_EDGES / 4;
    for (int i = blockIdx.x * 256 + tid; i < n4; i += nt) {
        int4 d = reinterpret_cast<const int4*>(dst)[i];
        int4 s = reinterpret_cast<const int4*>(src)[i];
        atomicAdd(&hd[d.x >> BSH], 1); atomicAdd(&hd[d.y >> BSH], 1);
        atomicAdd(&hd[d.z >> BSH], 1); atomicAdd(&hd[d.w >> BSH], 1);
        atomicAdd(&hs[s.x >> BSH], 1); atomicAdd(&hs[s.y >> BSH], 1);
        atomicAdd(&hs[s.z >> BSH], 1); atomicAdd(&hs[s.w >> BSH], 1);
    }
    __syncthreads();
    if (tid < NBUK) {
        if (hd[tid]) atomicAdd(&totD[tid], hd[tid]);
        if (hs[tid]) atomicAdd(&totS[tid], hs[tid]);
    }
}

// ---------------------------------------------------------------- K2: scan totals
__global__ __launch_bounds__(256) void scan_buckets(const int* __restrict__ totD,
                                                    const int* __restrict__ totS,
                                                    int* __restrict__ baseD,
                                                    int* __restrict__ baseS,
                                                    int* __restrict__ curD,
                                                    int* __restrict__ curS)
{
    __shared__ int sd[256], ss[256];
    const int t = threadIdx.x;
    int vd = (t < NBUK) ? totD[t] : 0;
    int vs = (t < NBUK) ? totS[t] : 0;
    sd[t] = vd; ss[t] = vs;
    __syncthreads();
    for (int off = 1; off < 256; off <<= 1) {
        int ud = (t >= off) ? sd[t - off] : 0;
        int us = (t >= off) ? ss[t - off] : 0;
        __syncthreads();
        sd[t] += ud; ss[t] += us;
        __syncthreads();
    }
    if (t < NBUK) {
        baseD[t] = sd[t] - vd; curD[t] = sd[t] - vd;
        baseS[t] = ss[t] - vs; curS[t] = ss[t] - vs;
    }
    if (t == NBUK - 1) { baseD[NBUK] = sd[t]; baseS[NBUK] = ss[t]; }
}

// ---------------------------------------------------------------- K3: partition
__global__ __launch_bounds__(512) void partition(const int* __restrict__ src,
                                                 const int* __restrict__ dst,
                                                 int* __restrict__ curD,
                                                 int* __restrict__ curS,
                                                 int2* __restrict__ bukD,
                                                 int* __restrict__ bukS)
{
    __shared__ int hd[NBUK], hs[NBUK], bd[NBUK], bs[NBUK], cd[NBUK], cs[NBUK];
    const int tid = threadIdx.x;
    const int chunk = (N_EDGES + gridDim.x - 1) / gridDim.x;
    const int beg = blockIdx.x * chunk;
    const int end = min(beg + chunk, N_EDGES);
    if (tid < NBUK) { hd[tid] = 0; hs[tid] = 0; cd[tid] = 0; cs[tid] = 0; }
    __syncthreads();
    for (int e = beg + tid; e < end; e += 512) {
        atomicAdd(&hd[dst[e] >> BSH], 1);
        atomicAdd(&hs[src[e] >> BSH], 1);
    }
    __syncthreads();
    if (tid < NBUK) {
        bd[tid] = hd[tid] ? atomicAdd(&curD[tid], hd[tid]) : 0;
        bs[tid] = hs[tid] ? atomicAdd(&curS[tid], hs[tid]) : 0;
    }
    __syncthreads();
    for (int e = beg + tid; e < end; e += 512) {
        int d = dst[e], s = src[e];
        int bin = d >> BSH;
        int r = atomicAdd(&cd[bin], 1);
        bukD[bd[bin] + r] = make_int2(d, s);
        int bin2 = s >> BSH;
        int r2 = atomicAdd(&cs[bin2], 1);
        bukS[bs[bin2] + r2] = s;
    }
}

// ---------------------------------------------------------------- K4: per-bucket CSR
__global__ __launch_bounds__(512) void csr_bucket(const int2* __restrict__ bukD,
                                                  const int* __restrict__ baseD,
                                                  int* __restrict__ row_ptr,
                                                  float* __restrict__ sin_,
                                                  int* __restrict__ col)
{
    __shared__ int h[BSZ], sc[BSZ], cur[BSZ];
    const int tid = threadIdx.x;
    const int n0 = blockIdx.x << BSH;
    const int lo = baseD[blockIdx.x], hi = baseD[blockIdx.x + 1];
    h[tid] = 0;
    __syncthreads();
    for (int i = lo + tid; i < hi; i += 512)
        atomicAdd(&h[bukD[i].x - n0], 1);
    __syncthreads();
    int own = h[tid];
    sc[tid] = own;
    __syncthreads();
    for (int off = 1; off < 512; off <<= 1) {
        int u = (tid >= off) ? sc[tid - off] : 0;
        __syncthreads();
        sc[tid] += u;
        __syncthreads();
    }
    int ex = sc[tid] - own;
    cur[tid] = ex;
    int node = n0 + tid;
    if (node <= N_NODES) row_ptr[node] = lo + ex;
    if (node < N_NODES)  sin_[node] = rsqrtf((float)max(own, 1));
    __syncthreads();
    for (int i = lo + tid; i < hi; i += 512) {
        int2 p = bukD[i];
        int r = atomicAdd(&cur[p.x - n0], 1);
        col[lo + r] = p.y;
    }
}

// ---------------------------------------------------------------- K5: out-degree
__global__ __launch_bounds__(512) void deg_bucket(const int* __restrict__ bukS,
                                                  const int* __restrict__ baseS,
                                                  float* __restrict__ sout)
{
    __shared__ int h[BSZ];
    const int tid = threadIdx.x;
    const int n0 = blockIdx.x << BSH;
    const int lo = baseS[blockIdx.x], hi = baseS[blockIdx.x + 1];
    h[tid] = 0;
    __syncthreads();
    for (int i = lo + tid; i < hi; i += 512)
        atomicAdd(&h[bukS[i] - n0], 1);
    __syncthreads();
    int node = n0 + tid;
    if (node < N_NODES) sout[node] = rsqrtf((float)max(h[tid], 1));
}

// ---------------------------------------------------------------- pack W into B-fragment order (hi/lo fp16)
// frag f = kc*8+ct; element (l, j): B[k= kc*32+(l>>4)*8+j][n= ct*16+(l&15)]
__global__ __launch_bounds__(256) void pack_w(const float* __restrict__ W,
                                              _Float16* __restrict__ hi,
                                              _Float16* __restrict__ lo)
{
    int idx = blockIdx.x * 256 + threadIdx.x;
    if (idx >= 16384) return;
    int f = idx >> 9, r = idx & 511;
    int l = r >> 3, j = r & 7;
    int kc = f >> 3, ct = f & 7;
    int k = kc * 32 + (l >> 4) * 8 + j;
    int n = ct * 16 + (l & 15);
    float w = W[k * 128 + n];
    _Float16 h = (_Float16)w;
    hi[idx] = h;
    lo[idx] = (_Float16)(w - (float)h);
}

// ---------------------------------------------------------------- MFMA GEMM, fp32 input (split hi/lo: 3 terms)
// Yh[N,128] = fp16( diag(srow) * (X @ W) ), fp32-exact via fp16x3 emulation.
// Block 256 = 4 waves; block tile 128 rows; wave: 32 rows (2 x 16-row tiles) x 128 cols.
// A-frags: direct global 16B loads (row-major matches A layout along k). B: packed table.
__global__ __launch_bounds__(256) void gemm_mfma_f32(const float* __restrict__ X,
                                                     const _Float16* __restrict__ Whi,
                                                     const _Float16* __restrict__ Wlo,
                                                     const float* __restrict__ srow,
                                                     _Float16* __restrict__ Y, int N)
{
    const int tid = threadIdx.x;
    const int l = tid & 63, w = tid >> 6;
    const int quad = l >> 4, m = l & 15;
    const int row0 = blockIdx.x * 128;
    const half8* Bh = reinterpret_cast<const half8*>(Whi);
    const half8* Bl = reinterpret_cast<const half8*>(Wlo);

    f32x4 acc[2][8] = {};

    for (int kc = 0; kc < 4; kc++) {
        half8 ah[2], al[2];
        #pragma unroll
        for (int rt = 0; rt < 2; rt++) {
            int grow = row0 + w * 32 + rt * 16 + m;
            float4 xa = make_float4(0.f, 0.f, 0.f, 0.f), xb = xa;
            if (grow < N) {
                const float4* Xp = reinterpret_cast<const float4*>(X) + (size_t)grow * 32 + kc * 8 + quad * 2;
                xa = Xp[0]; xb = Xp[1];
            }
            float xs[8] = {xa.x, xa.y, xa.z, xa.w, xb.x, xb.y, xb.z, xb.w};
            #pragma unroll
            for (int j = 0; j < 8; j++) {
                _Float16 h = (_Float16)xs[j];
                ah[rt][j] = h;
                al[rt][j] = (_Float16)(xs[j] - (float)h);
            }
        }
        #pragma unroll
        for (int ct = 0; ct < 8; ct++) {
            int f = kc * 8 + ct;
            half8 bh = Bh[f * 64 + l];
            half8 bl = Bl[f * 64 + l];
            #pragma unroll
            for (int rt = 0; rt < 2; rt++) {
                acc[rt][ct] = __builtin_amdgcn_mfma_f32_16x16x32_f16(ah[rt], bh, acc[rt][ct], 0, 0, 0);
                acc[rt][ct] = __builtin_amdgcn_mfma_f32_16x16x32_f16(al[rt], bh, acc[rt][ct], 0, 0, 0);
                acc[rt][ct] = __builtin_amdgcn_mfma_f32_16x16x32_f16(ah[rt], bl, acc[rt][ct], 0, 0, 0);
            }
        }
    }

    // C layout: col = l&15, row = quad*4 + reg
    #pragma unroll
    for (int rt = 0; rt < 2; rt++) {
        #pragma unroll
        for (int r = 0; r < 4; r++) {
            int grow = row0 + w * 32 + rt * 16 + quad * 4 + r;
            if (grow < N) {
                float s = srow[grow];
                #pragma unroll
                for (int ct = 0; ct < 8; ct++)
                    Y[(size_t)grow * 128 + ct * 16 + m] = (_Float16)(acc[rt][ct][r] * s);
            }
        }
    }
}

// ---------------------------------------------------------------- MFMA GEMM, fp16 input (exact: 2 terms)
__global__ __launch_bounds__(256) void gemm_mfma_f16(const _Float16* __restrict__ Xh,
                                                     const _Float16* __restrict__ Whi,
                                                     const _Float16* __restrict__ Wlo,
                                                     const float* __restrict__ srow,
                                                     _Float16* __restrict__ Y, int N)
{
    const int tid = threadIdx.x;
    const int l = tid & 63, w = tid >> 6;
    const int quad = l >> 4, m = l & 15;
    const int row0 = blockIdx.x * 128;
    const half8* Bh = reinterpret_cast<const half8*>(Whi);
    const half8* Bl = reinterpret_cast<const half8*>(Wlo);

    f32x4 acc[2][8] = {};

    for (int kc = 0; kc < 4; kc++) {
        half8 a[2];
        #pragma unroll
        for (int rt = 0; rt < 2; rt++) {
            int grow = row0 + w * 32 + rt * 16 + m;
            half8 z = {};
            a[rt] = (grow < N)
                ? *reinterpret_cast<const half8*>(Xh + (size_t)grow * 128 + kc * 32 + quad * 8)
                : z;
        }
        #pragma unroll
        for (int ct = 0; ct < 8; ct++) {
            int f = kc * 8 + ct;
            half8 bh = Bh[f * 64 + l];
            half8 bl = Bl[f * 64 + l];
            #pragma unroll
            for (int rt = 0; rt < 2; rt++) {
                acc[rt][ct] = __builtin_amdgcn_mfma_f32_16x16x32_f16(a[rt], bh, acc[rt][ct], 0, 0, 0);
                acc[rt][ct] = __builtin_amdgcn_mfma_f32_16x16x32_f16(a[rt], bl, acc[rt][ct], 0, 0, 0);
            }
        }
    }

    #pragma unroll
    for (int rt = 0; rt < 2; rt++) {
        #pragma unroll
        for (int r = 0; r < 4; r++) {
            int grow = row0 + w * 32 + rt * 16 + quad * 4 + r;
            if (grow < N) {
                float s = srow[grow];
                #pragma unroll
                for (int ct = 0; ct < 8; ct++)
                    Y[(size_t)grow * 128 + ct * 16 + m] = (_Float16)(acc[rt][ct][r] * s);
            }
        }
    }
}

// ---------------------------------------------------------------- gather-aggregate (fp16 in, fp16 out)
// one wave per node: Yh[n] = fp16( relu( (sum_{e} Hh[col[e]]) * sin_[n] + bias ) )
__global__ __launch_bounds__(256) void gather_agg(const __half* __restrict__ Hh,
                                                  const int* __restrict__ row_ptr,
                                                  const int* __restrict__ col,
                                                  const float* __restrict__ sin_,
                                                  const float* __restrict__ bias,
                                                  __half* __restrict__ Yh, int N)
{
    int node = blockIdx.x * 4 + (threadIdx.x >> 6);
    if (node >= N) return;
    int lane = threadIdx.x & 63;
    int beg = row_ptr[node], end = row_ptr[node + 1];
    const __half2* H2 = reinterpret_cast<const __half2*>(Hh);   // 64 half2 per row
    float2 acc0 = make_float2(0.f, 0.f);
    float2 acc1 = make_float2(0.f, 0.f);
    int i = beg;
    for (; i + 3 < end; i += 4) {
        int s0 = col[i], s1 = col[i + 1], s2 = col[i + 2], s3 = col[i + 3];
        __half2 v0 = H2[(size_t)s0 * 64 + lane];
        __half2 v1 = H2[(size_t)s1 * 64 + lane];
        __half2 v2 = H2[(size_t)s2 * 64 + lane];
        __half2 v3 = H2[(size_t)s3 * 64 + lane];
        float2 f0 = __half22float2(v0), f1 = __half22float2(v1);
        float2 f2 = __half22float2(v2), f3 = __half22float2(v3);
        acc0.x += f0.x + f1.x; acc0.y += f0.y + f1.y;
        acc1.x += f2.x + f3.x; acc1.y += f2.y + f3.y;
    }
    for (; i < end; i++) {
        int s = col[i];
        float2 f = __half22float2(H2[(size_t)s * 64 + lane]);
        acc0.x += f.x; acc0.y += f.y;
    }
    float sc = sin_[node];
    float2 b = reinterpret_cast<const float2*>(bias)[lane];
    float ox = fmaxf((acc0.x + acc1.x) * sc + b.x, 0.f);
    float oy = fmaxf((acc0.y + acc1.y) * sc + b.y, 0.f);
    reinterpret_cast<__half2*>(Yh)[(size_t)node * 64 + lane] = __floats2half2_rn(ox, oy);
}

// ---------------------------------------------------------------- classifier (fp16 in)
__global__ __launch_bounds__(256) void classifier(const __half* __restrict__ Hh,
                                                  const float* __restrict__ Wc,
                                                  const float* __restrict__ bc,
                                                  float* __restrict__ out, int N)
{
    __shared__ float4 Wcs[128];   // row k -> 4 cols
    for (int i = threadIdx.x; i < 128; i += 256)
        Wcs[i] = reinterpret_cast<const float4*>(Wc)[i];
    __syncthreads();
    int i = blockIdx.x * 256 + threadIdx.x;
    if (i < N) {
        float4 acc = reinterpret_cast<const float4*>(bc)[0];
        const __half2* h2 = reinterpret_cast<const __half2*>(Hh) + (size_t)i * 64;
        #pragma unroll
        for (int j = 0; j < 64; j++) {
            float2 f = __half22float2(h2[j]);
            float4 w0 = Wcs[2 * j], w1 = Wcs[2 * j + 1];
            acc.x += f.x * w0.x + f.y * w1.x;
            acc.y += f.x * w0.y + f.y * w1.y;
            acc.z += f.x * w0.z + f.y * w1.z;
            acc.w += f.x * w0.w + f.y * w1.w;
        }
        reinterpret_cast<float4*>(out)[i] = acc;
    }
}

// ---------------------------------------------------------------- launch
extern "C" void kernel_launch(void* const* d_in, const int* in_sizes, int n_in,
                              void* d_out, int out_size, void* d_ws, size_t ws_size,
                              hipStream_t stream)
{
    const float* features = (const float*)d_in[0];
    const int*   src      = (const int*)d_in[1];
    const int*   dst      = (const int*)d_in[2];
    const float* W1       = (const float*)d_in[3];
    const float* b1       = (const float*)d_in[4];
    const float* W2       = (const float*)d_in[5];
    const float* b2       = (const float*)d_in[6];
    const float* Wc       = (const float*)d_in[7];
    const float* bc       = (const float*)d_in[8];
    float* out = (float*)d_out;

    char* ws = (char*)d_ws;
    const size_t MB = 1 << 20;
    int* totD  = (int*)(ws + 0);
    int* totS  = (int*)(ws + 1024);
    int* baseD = (int*)(ws + 2048);
    int* baseS = (int*)(ws + 3072);
    int* curD  = (int*)(ws + 4096);
    int* curS  = (int*)(ws + 5120);
    float* sout    = (float*)(ws + 1 * MB);          // N floats
    float* sin_    = (float*)(ws + 2 * MB);          // N floats
    int*   row_ptr = (int*)(ws + 3 * MB);            // N+1 ints
    int*   col     = (int*)(ws + 4 * MB);            // E ints (6.4 MB)
    int2*  bukD    = (int2*)(ws + 11 * MB);          // E pairs (12.8 MB) — dead after csr_bucket
    int*   bukS    = (int*)(ws + 24 * MB);           // E ints (6.4 MB)  — dead after deg_bucket
    _Float16* Whi1 = (_Float16*)(ws + 31 * MB);              // 32 KB
    _Float16* Wlo1 = (_Float16*)(ws + 31 * MB + 32 * 1024);  // 32 KB
    _Float16* Whi2 = (_Float16*)(ws + 31 * MB + 64 * 1024);  // 32 KB
    _Float16* Wlo2 = (_Float16*)(ws + 31 * MB + 96 * 1024);  // 32 KB
    _Float16* hMsg = (_Float16*)(ws + 32 * MB);      // [N,128] fp16 (25.6 MB)
    _Float16* hA   = (_Float16*)(ws + 58 * MB);      // [N,128] fp16 (25.6 MB)

    const int N = N_NODES;
    const int GBLK = (N + 127) / 128;                // 782

    // ---- CSR build + degree norms (bucket counting sort)
    hipMemsetAsync(ws, 0, 2048, stream);             // totD, totS
    hist_buckets<<<392, 256, 0, stream>>>(src, dst, totD, totS);
    scan_buckets<<<1, 256, 0, stream>>>(totD, totS, baseD, baseS, curD, curS);
    partition<<<NBUK, 512, 0, stream>>>(src, dst, curD, curS, bukD, bukS);
    csr_bucket<<<NBUK, 512, 0, stream>>>(bukD, baseD, row_ptr, sin_, col);
    deg_bucket<<<NBUK, 512, 0, stream>>>(bukS, baseS, sout);

    // ---- pack weights into MFMA B-fragment order (fp16 hi/lo)
    pack_w<<<64, 256, 0, stream>>>(W1, Whi1, Wlo1);
    pack_w<<<64, 256, 0, stream>>>(W2, Whi2, Wlo2);

    // ---- layer 1
    gemm_mfma_f32<<<GBLK, 256, 0, stream>>>(features, Whi1, Wlo1, sout, hMsg, N);
    gather_agg<<<(N + 3) / 4, 256, 0, stream>>>((const __half*)hMsg, row_ptr, col, sin_, b1, (__half*)hA, N);

    // ---- layer 2
    gemm_mfma_f16<<<GBLK, 256, 0, stream>>>(hA, Whi2, Wlo2, sout, hMsg, N);
    gather_agg<<<(N + 3) / 4, 256, 0, stream>>>((const __half*)hMsg, row_ptr, col, sin_, b2, (__half*)hA, N);

    // ---- classifier
    classifier<<<(N + 255) / 256, 256, 0, stream>>>((const __half*)hA, Wc, bc, out, N);
}